// Round 4
// baseline (449.212 us; speedup 1.0000x reference)
//
#include <hip/hip_runtime.h>
#include <hip/hip_bf16.h>

#define DEVI __device__ __forceinline__

typedef __attribute__((ext_vector_type(8))) short bf16x8;
typedef __attribute__((ext_vector_type(4))) float f32x4;
typedef unsigned short u16;
typedef unsigned long long u64;

// ---------------- helpers ----------------

DEVI void async16(const void* g, const void* l) {
  __builtin_amdgcn_global_load_lds(
      (const __attribute__((address_space(1))) unsigned int*)g,
      (__attribute__((address_space(3))) unsigned int*)l, 16, 0, 0);
}

DEVI u16 f2bf(float x) {  // RNE f32->bf16 (finite inputs only)
  unsigned int u = __float_as_uint(x);
  return (u16)((u + 0x7fffu + ((u >> 16) & 1u)) >> 16);
}

DEVI float fast_exp2(float x) {
#if __has_builtin(__builtin_amdgcn_exp2f)
  return __builtin_amdgcn_exp2f(x);  // raw v_exp_f32, no libm wrapper
#else
  return exp2f(x);
#endif
}

// pack two f32 (trunc) into one u32 of 2x bf16: low=lo, high=hi
DEVI unsigned pk_bf16(unsigned hi, unsigned lo) {
#if __has_builtin(__builtin_amdgcn_perm)
  return __builtin_amdgcn_perm(hi, lo, 0x07060302u);  // v_perm_b32: {hi.b3,hi.b2,lo.b3,lo.b2}
#else
  return (hi & 0xffff0000u) | (lo >> 16);
#endif
}

// AND-word for 2 mask bits k,k+1 of byte b: low16 = bit k (0->keep), high16 = bit k+1
DEVI unsigned mk2(unsigned b, int k) {
  return ((((b >> k) & 1u) ? 0u : 0x0000FFFFu) | (((b >> (k + 1)) & 1u) ? 0u : 0xFFFF0000u));
}

// ---------------- fused prep kernel ----------------
// blocks [0,8192)       cast ctx -> Xc
// blocks [8192,16384)   cast val -> Xv
// blocks [16384,17408)  cast Wo  -> WoB
// blocks [17408,18176)  LDS-tiled transpose Wq/Wk/Wv -> Wqt/Wkt/Wvt (bf16)
// blocks [18176,34560)  mask bit-pack (TRANSPOSED: mbits[word][row]) — 512 KB total
// blocks [34560,34568)  bias concat bq|bk -> bqk
// (R2/R3's 8 MB bf16 AND-table is gone: 512 KB/block streaming made attn mem-bound)

__global__ __launch_bounds__(256) void prep_kernel(
    const float* __restrict__ ctx, const float* __restrict__ val, const int* __restrict__ msk,
    const float* __restrict__ Wq, const float* __restrict__ Wk, const float* __restrict__ Wv,
    const float* __restrict__ Wo, const float* __restrict__ bq, const float* __restrict__ bk,
    u16* __restrict__ Xc, u16* __restrict__ Xv, u16* __restrict__ Wqt, u16* __restrict__ Wkt,
    u16* __restrict__ Wvt, u16* __restrict__ WoB, u64* __restrict__ mbits, float* __restrict__ bqk) {
  __shared__ float tile[64 * 69];
  const int blk = blockIdx.x, tid = threadIdx.x;
  if (blk < 16384) {
    const float* src = (blk < 8192) ? ctx : val;
    u16* dst = (blk < 8192) ? Xc : Xv;
    int i = (blk & 8191) * 256 + tid;
    float4 v = ((const float4*)src)[i];
    ushort4 o;
    o.x = f2bf(v.x); o.y = f2bf(v.y); o.z = f2bf(v.z); o.w = f2bf(v.w);
    ((ushort4*)dst)[i] = o;
  } else if (blk < 17408) {
    int i = (blk - 16384) * 256 + tid;
    float4 v = ((const float4*)Wo)[i];
    ushort4 o;
    o.x = f2bf(v.x); o.y = f2bf(v.y); o.z = f2bf(v.z); o.w = f2bf(v.w);
    ((ushort4*)WoB)[i] = o;
  } else if (blk < 18176) {
    // W [H=16][1024 d][64 k] -> Wt [h*64+k][1024 d]; 256 blocks per matrix
    int t = blk - 17408;
    int mat = t >> 8, r = t & 255, h = r >> 4, d0 = (r & 15) * 64;
    const float* Ws = (mat == 0) ? Wq : (mat == 1) ? Wk : Wv;
    u16* Wd = (mat == 0) ? Wqt : (mat == 1) ? Wkt : Wvt;
    const int dg = tid & 15, rg = tid >> 4;
#pragma unroll
    for (int i = 0; i < 4; i++) {
      int dr = rg + i * 16;
      float4 v = *(const float4*)&Ws[((size_t)(h * 1024 + d0 + dr)) * 64 + dg * 4];
      tile[dr * 69 + dg * 4 + 0] = v.x;
      tile[dr * 69 + dg * 4 + 1] = v.y;
      tile[dr * 69 + dg * 4 + 2] = v.z;
      tile[dr * 69 + dg * 4 + 3] = v.w;
    }
    __syncthreads();
#pragma unroll
    for (int i = 0; i < 4; i++) {
      int k = rg + i * 16;
      ushort4 o;
      o.x = f2bf(tile[(dg * 4 + 0) * 69 + k]);
      o.y = f2bf(tile[(dg * 4 + 1) * 69 + k]);
      o.z = f2bf(tile[(dg * 4 + 2) * 69 + k]);
      o.w = f2bf(tile[(dg * 4 + 3) * 69 + k]);
      *(ushort4*)&Wd[(size_t)(h * 64 + k) * 1024 + d0 + dg * 4] = o;
    }
  } else if (blk < 34560) {
    int gid = (blk - 18176) * 256 + tid;  // gid = row*2048 + col over [S][S]
    u64 bal = __ballot(msk[gid] == 1);
    if ((tid & 63) == 0) mbits[(size_t)((gid >> 6) & 31) * 2048 + (gid >> 11)] = bal;
  } else {
    int i = (blk - 34560) * 256 + tid;  // 0..2047
    bqk[i] = (i < 1024) ? bq[i] : bk[i - 1024];
  }
}

// ---------------- fused QKV projection GEMM ----------------
// grid (64, 24). y<16: QK half — C_qk[M][2048] bf16 = Xc*Wqkt^T (+bqk), Q cols scaled.
// y>=16: V half — Vtg[bh][dk][S] bf16 transposed = Xv*Wvt^T (+bv).
// 128x128 tile, BK=32, 4 waves, global_load_lds staging (m97 structure).

__global__ __launch_bounds__(256) void qkv_gemm(const u16* __restrict__ Xc, const u16* __restrict__ Xv,
                                                const u16* __restrict__ Wqkt, const u16* __restrict__ Wvt,
                                                const float* __restrict__ bqk, const float* __restrict__ bvv,
                                                u16* __restrict__ QKb, u16* __restrict__ Vtg, float qscale) {
  __shared__ __align__(16) u16 As[128 * 32];
  __shared__ __align__(16) u16 Bs[128 * 32];
  const int tid = threadIdx.x;
  const int w = tid >> 6, lane = tid & 63, quad = lane >> 4, lc = lane & 15;
  const int K = 1024;
  const bool isV = blockIdx.y >= 16;
  const int m0 = blockIdx.x * 128;
  const int n0 = (isV ? (blockIdx.y - 16) : blockIdx.y) * 128;
  const u16* A  = isV ? Xv : Xc;
  const u16* Bt = isV ? Wvt : Wqkt;
  const float* bias = isV ? bvv : bqk;
  const int wrow = (w >> 1) * 64, wcol = (w & 1) * 64;
  const int srow = tid >> 2, sc = tid & 3;
  const u16* Ag = A + (size_t)(m0 + srow) * K + sc * 8;
  const u16* Bg = Bt + (size_t)(n0 + srow) * K + sc * 8;
  u16* Asw = As + w * 512;
  u16* Bsw = Bs + w * 512;

  f32x4 acc[4][4] = {};
  for (int k0 = 0; k0 < K; k0 += 32) {
    async16(Ag + k0, Asw);
    async16(Ag + k0 + (size_t)64 * K, Asw + 2048);
    async16(Bg + k0, Bsw);
    async16(Bg + k0 + (size_t)64 * K, Bsw + 2048);
    __syncthreads();
    bf16x8 af[4], bfr[4];
#pragma unroll
    for (int rt = 0; rt < 4; rt++) af[rt] = *(const bf16x8*)&As[(wrow + rt * 16 + lc) * 32 + quad * 8];
#pragma unroll
    for (int ct = 0; ct < 4; ct++) bfr[ct] = *(const bf16x8*)&Bs[(wcol + ct * 16 + lc) * 32 + quad * 8];
#pragma unroll
    for (int rt = 0; rt < 4; rt++)
#pragma unroll
      for (int ct = 0; ct < 4; ct++)
        acc[rt][ct] = __builtin_amdgcn_mfma_f32_16x16x32_bf16(af[rt], bfr[ct], acc[rt][ct], 0, 0, 0);
    __syncthreads();
  }
#pragma unroll
  for (int ct = 0; ct < 4; ct++) {
    int col = n0 + wcol + ct * 16 + lc;
    float bv = bias[col];
    float os = (!isV && col < 1024) ? qscale : 1.0f;
#pragma unroll
    for (int rt = 0; rt < 4; rt++) {
      if (isV) {
        int trow = m0 + wrow + rt * 16 + quad * 4;  // 4-aligned, never crosses 2048
        ushort4 pk;
        pk.x = f2bf(acc[rt][ct][0] + bv);
        pk.y = f2bf(acc[rt][ct][1] + bv);
        pk.z = f2bf(acc[rt][ct][2] + bv);
        pk.w = f2bf(acc[rt][ct][3] + bv);
        size_t off = ((size_t)(trow >> 11) * 1024 + col) * 2048 + (trow & 2047);
        *(ushort4*)(Vtg + off) = pk;
      } else {
#pragma unroll
        for (int r = 0; r < 4; r++) {
          int row = m0 + wrow + rt * 16 + quad * 4 + r;
          QKb[(size_t)row * 2048 + col] = f2bf((acc[rt][ct][r] + bv) * os);
        }
      }
    }
  }
}

// ---------------- flash attention v8 ----------------
// grid (S/128 = 16, B*H = 64) — exactly 4 blocks/CU. Block 256 = 4 waves,
// each wave owns 32 q-rows (2 strips of 16).
//
// v8 mask path: bit-packed mbits (dense, 32 KB/block global traffic) expanded
// to bf16 AND-words via a 256-entry LDS lookup table (byte -> uint4 of FF/00
// words, 4 KB, content-independent, built once per block). Per tile/wave:
// 2 coalesced u64 loads + 4 shifts + 4 ds_read_b128 — replaces both R1's
// ~90 VALU cndmask masking and R2/R3's 512 KB/block bf16-table streaming
// (which made attn memory-bound: WRITE_SIZE 394 MB).
//  - exp on raw scores, mask applied as AND on packed bf16 pairs
//  - sacc zero-init folded into first MFMA's C operand
//  - #pragma unroll 2 on K/V loop: `cur` compile-time, LDS addrs fold
// QK: bf16 [B*S][2048] (cols 0-1023 Q pre-scaled by 0.125*log2e, 1024-2047 K).
// Vt: bf16 [bh][dk][S]. PERMUTED K staging (v5) so post-exp P is lane-local
// and in PV A-fragment order. No max-subtraction. LDS 36 KB -> 4 blocks/CU.

__global__ __launch_bounds__(256, 4) void attn_kernel(const u16* __restrict__ QK, const u16* __restrict__ Vt,
                                                      const u64* __restrict__ mbits, u16* __restrict__ AO) {
  __shared__ __align__(16) u16 Ks[2][4096];
  __shared__ __align__(16) u16 Vs[2][4096];
  __shared__ uint4 Tbl[256];  // byte -> 4 AND-words (8 bf16 lanes of FF/00)
  const int S = 2048, D = 1024, QS = 2048;
  const int tid = threadIdx.x, w = tid >> 6, lane = tid & 63, quad = lane >> 4, lc = lane & 15;
  const int q0 = blockIdx.x * 128;
  const int b = blockIdx.y >> 4, h = blockIdx.y & 15;
  const size_t baseq = (size_t)b * S * QS + (size_t)h * 64;
  const size_t vbase = (size_t)blockIdx.y * 64 * S;
  const int sr = lane >> 3, gch = (lane & 7) ^ sr, lx = lc & 7;
  u16* Ksq = (u16*)Ks;  // 16 KB = 128 rows x 64 — Q pre-stage area

  // build mask-expansion table (mask-content independent): one entry per thread
  {
    unsigned bv = (unsigned)tid;
    uint4 e;
    e.x = mk2(bv, 0); e.y = mk2(bv, 2); e.z = mk2(bv, 4); e.w = mk2(bv, 6);
    Tbl[bv] = e;
  }

  // stage Q (wave w: rows q0+w*32 .. +31) into Ks region, chunk-XOR swizzled
#pragma unroll
  for (int i = 0; i < 4; i++) {
    const u16* g = QK + baseq + (size_t)(q0 + w * 32 + i * 8 + sr) * QS + gch * 8;
    async16(g, Ksq + w * 2048 + i * 512);
  }
  // permuted K source row for this lane: LDS slot s=16w+8i+sr holds key
  // 32(w&1)+4(w>>1) + 16i + 8(sr>>2) + (sr&3)  (see PV-fragment derivation)
  const int kperm = 32 * (w & 1) + 4 * (w >> 1) + 8 * (sr >> 2) + (sr & 3);
  const u16* Kg0 = QK + baseq + 1024 + (size_t)kperm * QS + gch * 8;
  const u16* Vg0 = Vt + vbase + (size_t)(w * 16 + sr) * S + gch * 8;
  __syncthreads();  // Q staged (also publishes Tbl)

  // Q fragments -> registers: aq[strip][ks]
  bf16x8 aq[2][2];
#pragma unroll
  for (int s = 0; s < 2; s++)
#pragma unroll
    for (int ks = 0; ks < 2; ks++)
      aq[s][ks] = *(const bf16x8*)&Ksq[w * 2048 + (s * 16 + lc) * 64 + (((ks * 4 + quad) ^ lx) << 3)];
  __syncthreads();  // all aq reads done before K staging overwrites region

  // prefetch tile 0 (K rows permuted: i=0 -> +0, i=1 -> +16 rows)
  async16(Kg0, Ks[0] + w * 1024);
  async16(Kg0 + (size_t)16 * QS, Ks[0] + w * 1024 + 512);
  async16(Vg0, Vs[0] + w * 1024);
  async16(Vg0 + (size_t)8 * S, Vs[0] + w * 1024 + 512);

  // mask word pointer: row = q0+w*32+lc (strip 0), +16 (strip 1); word = t0/64
  const u64* mptr = mbits + (size_t)(q0 + w * 32 + lc);
  const int sh8 = quad << 3;

  bf16x8 ones;
#pragma unroll
  for (int j = 0; j < 8; j++) ones[j] = (short)0x3F80;  // bf16 1.0

  const f32x4 z = {};  // hoisted zero quad: C operand for first MFMA of each chain
  f32x4 acco[2][4] = {};
  f32x4 accl[2] = {};

#pragma unroll 2
  for (int t0 = 0; t0 < S; t0 += 64) {
    const int cur = (t0 >> 6) & 1;
    __syncthreads();  // buf[cur] staged; all waves done with buf[cur^1]
    if (t0 + 64 < S) {
      const u16* Kg = Kg0 + (size_t)(t0 + 64) * QS;
      const u16* Vg = Vg0 + (t0 + 64);
      async16(Kg, Ks[cur ^ 1] + w * 1024);
      async16(Kg + (size_t)16 * QS, Ks[cur ^ 1] + w * 1024 + 512);
      async16(Vg, Vs[cur ^ 1] + w * 1024);
      async16(Vg + (size_t)8 * S, Vs[cur ^ 1] + w * 1024 + 512);
    }

    // mask words for this tile (issue early; consumed after QK)
    u64 mw0 = mptr[(size_t)(t0 >> 6) * 2048];
    u64 mw1 = mptr[(size_t)(t0 >> 6) * 2048 + 16];

    // swapped QK^T: sacc[s][ct][r] = S^T[key slot ct*16+quad*4+r][q=lc]
    // first MFMA of each chain takes C=z (no per-tile zero-init movs)
    f32x4 sacc[2][4];
    __builtin_amdgcn_s_setprio(1);
#pragma unroll
    for (int ct = 0; ct < 4; ct++) {  // ks = 0
      bf16x8 bk = *(const bf16x8*)&Ks[cur][(ct * 16 + lc) * 64 + ((quad ^ lx) << 3)];
      sacc[0][ct] = __builtin_amdgcn_mfma_f32_16x16x32_bf16(bk, aq[0][0], z, 0, 0, 0);
      sacc[1][ct] = __builtin_amdgcn_mfma_f32_16x16x32_bf16(bk, aq[1][0], z, 0, 0, 0);
    }
#pragma unroll
    for (int ct = 0; ct < 4; ct++) {  // ks = 1
      bf16x8 bk = *(const bf16x8*)&Ks[cur][(ct * 16 + lc) * 64 + (((4 + quad) ^ lx) << 3)];
      sacc[0][ct] = __builtin_amdgcn_mfma_f32_16x16x32_bf16(bk, aq[0][1], sacc[0][ct], 0, 0, 0);
      sacc[1][ct] = __builtin_amdgcn_mfma_f32_16x16x32_bf16(bk, aq[1][1], sacc[1][ct], 0, 0, 0);
    }
    __builtin_amdgcn_s_setprio(0);

    // per strip: table-lookup AND-masks; exp (unmasked) -> pack -> AND -> PV
#pragma unroll
    for (int s = 0; s < 2; s++) {
      const u64 mw = s ? mw1 : mw0;
      // f0 keys t0+8q+0..7 = byte q of lo; f1 keys t0+32+8q+0..7 = byte q of hi
      uint4 ma = Tbl[((unsigned)mw >> sh8) & 255u];
      uint4 mb = Tbl[((unsigned)(mw >> 32) >> sh8) & 255u];
      unsigned pu[4][4];
#pragma unroll
      for (int ct = 0; ct < 4; ct++)
#pragma unroll
        for (int r = 0; r < 4; r++)
          pu[ct][r] = __float_as_uint(fast_exp2(sacc[s][ct][r]));
      // frag[ks] keys 32ks+8quad+{0..7}; AND-words in key-sequential pair order
      union { unsigned u[4]; bf16x8 v; } f0, f1;
      f0.u[0] = pk_bf16(pu[0][1], pu[0][0]) & ma.x;
      f0.u[1] = pk_bf16(pu[0][3], pu[0][2]) & ma.y;
      f0.u[2] = pk_bf16(pu[2][1], pu[2][0]) & ma.z;
      f0.u[3] = pk_bf16(pu[2][3], pu[2][2]) & ma.w;
      f1.u[0] = pk_bf16(pu[1][1], pu[1][0]) & mb.x;
      f1.u[1] = pk_bf16(pu[1][3], pu[1][2]) & mb.y;
      f1.u[2] = pk_bf16(pu[3][1], pu[3][0]) & mb.z;
      f1.u[3] = pk_bf16(pu[3][3], pu[3][2]) & mb.w;

      __builtin_amdgcn_s_setprio(1);
#pragma unroll
      for (int ct = 0; ct < 4; ct++) {
        bf16x8 bv = *(const bf16x8*)&Vs[cur][(ct * 16 + lc) * 64 + ((quad ^ lx) << 3)];
        acco[s][ct] = __builtin_amdgcn_mfma_f32_16x16x32_bf16(f0.v, bv, acco[s][ct], 0, 0, 0);
      }
      accl[s] = __builtin_amdgcn_mfma_f32_16x16x32_bf16(f0.v, ones, accl[s], 0, 0, 0);
#pragma unroll
      for (int ct = 0; ct < 4; ct++) {
        bf16x8 bv = *(const bf16x8*)&Vs[cur][(ct * 16 + lc) * 64 + (((4 + quad) ^ lx) << 3)];
        acco[s][ct] = __builtin_amdgcn_mfma_f32_16x16x32_bf16(f1.v, bv, acco[s][ct], 0, 0, 0);
      }
      accl[s] = __builtin_amdgcn_mfma_f32_16x16x32_bf16(f1.v, ones, accl[s], 0, 0, 0);
      __builtin_amdgcn_s_setprio(0);
    }
  }

#pragma unroll
  for (int s = 0; s < 2; s++)
#pragma unroll
    for (int r = 0; r < 4; r++) {
      float inv = 1.0f / accl[s][r];
      size_t row = (size_t)b * S + q0 + w * 32 + s * 16 + quad * 4 + r;
#pragma unroll
      for (int ct = 0; ct < 4; ct++)
        AO[row * D + h * 64 + ct * 16 + lc] = f2bf(acco[s][ct][r] * inv);
    }
}

// ---------------- output projection GEMM (f32 out) ----------------

__global__ __launch_bounds__(256) void out_gemm(const u16* __restrict__ A, const u16* __restrict__ Bt,
                                                const float* __restrict__ bias, float* __restrict__ C) {
  __shared__ __align__(16) u16 As[128 * 32];
  __shared__ __align__(16) u16 Bs[128 * 32];
  const int tid = threadIdx.x;
  const int w = tid >> 6, lane = tid & 63, quad = lane >> 4, lc = lane & 15;
  const int K = 1024, N = 1024;
  const int m0 = blockIdx.x * 128, n0 = blockIdx.y * 128;
  const int wrow = (w >> 1) * 64, wcol = (w & 1) * 64;
  const int srow = tid >> 2, sc = tid & 3;
  const u16* Ag = A + (size_t)(m0 + srow) * K + sc * 8;
  const u16* Bg = Bt + (size_t)(n0 + srow) * K + sc * 8;
  u16* Asw = As + w * 512;
  u16* Bsw = Bs + w * 512;

  f32x4 acc[4][4] = {};
  for (int k0 = 0; k0 < K; k0 += 32) {
    async16(Ag + k0, Asw);
    async16(Ag + k0 + (size_t)64 * K, Asw + 2048);
    async16(Bg + k0, Bsw);
    async16(Bg + k0 + (size_t)64 * K, Bsw + 2048);
    __syncthreads();
    bf16x8 af[4], bfr[4];
#pragma unroll
    for (int rt = 0; rt < 4; rt++) af[rt] = *(const bf16x8*)&As[(wrow + rt * 16 + lc) * 32 + quad * 8];
#pragma unroll
    for (int ct = 0; ct < 4; ct++) bfr[ct] = *(const bf16x8*)&Bs[(wcol + ct * 16 + lc) * 32 + quad * 8];
#pragma unroll
    for (int rt = 0; rt < 4; rt++)
#pragma unroll
      for (int ct = 0; ct < 4; ct++)
        acc[rt][ct] = __builtin_amdgcn_mfma_f32_16x16x32_bf16(af[rt], bfr[ct], acc[rt][ct], 0, 0, 0);
    __syncthreads();
  }
#pragma unroll
  for (int ct = 0; ct < 4; ct++) {
    int col = n0 + wcol + ct * 16 + lc;
    float bv = bias[col];
#pragma unroll
    for (int rt = 0; rt < 4; rt++)
#pragma unroll
      for (int r = 0; r < 4; r++) {
        int row = m0 + wrow + rt * 16 + quad * 4 + r;
        C[(size_t)row * N + col] = acc[rt][ct][r] + bv;
      }
  }
}

// ---------------- launcher ----------------

extern "C" void kernel_launch(void* const* d_in, const int* in_sizes, int n_in,
                              void* d_out, int out_size, void* d_ws, size_t ws_size,
                              hipStream_t stream) {
  const int B = 4, S = 2048, D = 1024;
  const float* ctx = (const float*)d_in[0];
  const float* val = (const float*)d_in[1];
  const int*   msk = (const int*)d_in[2];
  const float* Wq  = (const float*)d_in[3];
  const float* bq  = (const float*)d_in[4];
  const float* Wk  = (const float*)d_in[5];
  const float* bk  = (const float*)d_in[6];
  const float* Wv  = (const float*)d_in[7];
  const float* bv  = (const float*)d_in[8];
  const float* Wo  = (const float*)d_in[9];
  const float* bo  = (const float*)d_in[10];
  float* out = (float*)d_out;

  char* ws = (char*)d_ws;
  size_t off = 0;
  auto alloc = [&](size_t sz) { void* p = ws + off; off += (sz + 255) & ~255ULL; return p; };
  const size_t NTOK = (size_t)B * S * D;  // 8388608
  u16* Xc  = (u16*)alloc(NTOK * 2);
  u16* Xv  = (u16*)alloc(NTOK * 2);
  u16* Wqt = (u16*)alloc((size_t)D * D * 2);   // Wqt/Wkt contiguous: fused B matrix
  u16* Wkt = (u16*)alloc((size_t)D * D * 2);
  u16* Wvt = (u16*)alloc((size_t)D * D * 2);
  u16* WoB = (u16*)alloc((size_t)D * D * 2);
  u16* QKb = (u16*)alloc(NTOK * 4);            // fused QK output [B*S][2048]
  u16* Vtg = (u16*)alloc(NTOK * 2);            // V transposed: [bh][dk][S]
  u64* mbits = (u64*)alloc((size_t)S * S / 8); // transposed: [word 0..31][row 0..2047]
  float* bqk = (float*)alloc(2048 * 4);
  u16* AO = Xc;  // alias: Xc dead after QKV GEMM (before attention runs)
  if (off > ws_size) return;  // workspace too small -> visible failure, no OOB

  const float qscale = 0.125f * 1.44269504088896f;  // 1/sqrt(DK) * log2(e)

  prep_kernel<<<34568, 256, 0, stream>>>(ctx, val, msk, Wq, Wk, Wv, Wo, bq, bk,
                                         Xc, Xv, Wqt, Wkt, Wvt, WoB, mbits, bqk);

  // fused Q|K|V projections (QK half N=2048 over Xc; V half N=1024 over Xv, transposed out)
  qkv_gemm<<<dim3(B * S / 128, 24), 256, 0, stream>>>(Xc, Xv, Wqt, Wvt, bqk, bv, QKb, Vtg, qscale);

  // attention
  attn_kernel<<<dim3(S / 128, B * 16), 256, 0, stream>>>(QKb, Vtg, mbits, AO);

  // output projection (f32 out)
  out_gemm<<<dim3(B * S / 128, D / 128), 256, 0, stream>>>(AO, WoB, bo, out);
}

// Round 5
// 340.879 us; speedup vs baseline: 1.3178x; 1.3178x over previous
//
#include <hip/hip_runtime.h>
#include <hip/hip_bf16.h>

#define DEVI __device__ __forceinline__

typedef __attribute__((ext_vector_type(8))) short bf16x8;
typedef __attribute__((ext_vector_type(4))) float f32x4;
typedef unsigned short u16;
typedef unsigned long long u64;

// ---------------- helpers ----------------

DEVI void async16(const void* g, const void* l) {
  __builtin_amdgcn_global_load_lds(
      (const __attribute__((address_space(1))) unsigned int*)g,
      (__attribute__((address_space(3))) unsigned int*)l, 16, 0, 0);
}

DEVI u16 f2bf(float x) {  // RNE f32->bf16 (finite inputs only)
  unsigned int u = __float_as_uint(x);
  return (u16)((u + 0x7fffu + ((u >> 16) & 1u)) >> 16);
}

DEVI float fast_exp2(float x) {
#if __has_builtin(__builtin_amdgcn_exp2f)
  return __builtin_amdgcn_exp2f(x);  // raw v_exp_f32, no libm wrapper
#else
  return exp2f(x);
#endif
}

// pack two f32 (trunc) into one u32 of 2x bf16: low=lo, high=hi
DEVI unsigned pk_bf16(unsigned hi, unsigned lo) {
#if __has_builtin(__builtin_amdgcn_perm)
  return __builtin_amdgcn_perm(hi, lo, 0x07060302u);  // v_perm_b32: {hi.b3,hi.b2,lo.b3,lo.b2}
#else
  return (hi & 0xffff0000u) | (lo >> 16);
#endif
}

// AND-word for 2 mask bits k,k+1 of byte b: low16 = bit k (0->keep), high16 = bit k+1
DEVI unsigned mk2(unsigned b, int k) {
  return ((((b >> k) & 1u) ? 0u : 0x0000FFFFu) | (((b >> (k + 1)) & 1u) ? 0u : 0xFFFF0000u));
}

// ---------------- fused prep kernel ----------------
// blocks [0,8192)       cast ctx -> Xc
// blocks [8192,16384)   cast val -> Xv
// blocks [16384,17408)  cast Wo  -> WoB
// blocks [17408,18176)  LDS-tiled transpose Wq/Wk/Wv -> Wqt/Wkt/Wvt (bf16)
// blocks [18176,34560)  mask bit-pack (TRANSPOSED: mbits[word][row]) — 512 KB total
// blocks [34560,34568)  bias concat bq|bk -> bqk

__global__ __launch_bounds__(256) void prep_kernel(
    const float* __restrict__ ctx, const float* __restrict__ val, const int* __restrict__ msk,
    const float* __restrict__ Wq, const float* __restrict__ Wk, const float* __restrict__ Wv,
    const float* __restrict__ Wo, const float* __restrict__ bq, const float* __restrict__ bk,
    u16* __restrict__ Xc, u16* __restrict__ Xv, u16* __restrict__ Wqt, u16* __restrict__ Wkt,
    u16* __restrict__ Wvt, u16* __restrict__ WoB, u64* __restrict__ mbits, float* __restrict__ bqk) {
  __shared__ float tile[64 * 69];
  const int blk = blockIdx.x, tid = threadIdx.x;
  if (blk < 16384) {
    const float* src = (blk < 8192) ? ctx : val;
    u16* dst = (blk < 8192) ? Xc : Xv;
    int i = (blk & 8191) * 256 + tid;
    float4 v = ((const float4*)src)[i];
    ushort4 o;
    o.x = f2bf(v.x); o.y = f2bf(v.y); o.z = f2bf(v.z); o.w = f2bf(v.w);
    ((ushort4*)dst)[i] = o;
  } else if (blk < 17408) {
    int i = (blk - 16384) * 256 + tid;
    float4 v = ((const float4*)Wo)[i];
    ushort4 o;
    o.x = f2bf(v.x); o.y = f2bf(v.y); o.z = f2bf(v.z); o.w = f2bf(v.w);
    ((ushort4*)WoB)[i] = o;
  } else if (blk < 18176) {
    // W [H=16][1024 d][64 k] -> Wt [h*64+k][1024 d]; 256 blocks per matrix
    int t = blk - 17408;
    int mat = t >> 8, r = t & 255, h = r >> 4, d0 = (r & 15) * 64;
    const float* Ws = (mat == 0) ? Wq : (mat == 1) ? Wk : Wv;
    u16* Wd = (mat == 0) ? Wqt : (mat == 1) ? Wkt : Wvt;
    const int dg = tid & 15, rg = tid >> 4;
#pragma unroll
    for (int i = 0; i < 4; i++) {
      int dr = rg + i * 16;
      float4 v = *(const float4*)&Ws[((size_t)(h * 1024 + d0 + dr)) * 64 + dg * 4];
      tile[dr * 69 + dg * 4 + 0] = v.x;
      tile[dr * 69 + dg * 4 + 1] = v.y;
      tile[dr * 69 + dg * 4 + 2] = v.z;
      tile[dr * 69 + dg * 4 + 3] = v.w;
    }
    __syncthreads();
#pragma unroll
    for (int i = 0; i < 4; i++) {
      int k = rg + i * 16;
      ushort4 o;
      o.x = f2bf(tile[(dg * 4 + 0) * 69 + k]);
      o.y = f2bf(tile[(dg * 4 + 1) * 69 + k]);
      o.z = f2bf(tile[(dg * 4 + 2) * 69 + k]);
      o.w = f2bf(tile[(dg * 4 + 3) * 69 + k]);
      *(ushort4*)&Wd[(size_t)(h * 64 + k) * 1024 + d0 + dg * 4] = o;
    }
  } else if (blk < 34560) {
    int gid = (blk - 18176) * 256 + tid;  // gid = row*2048 + col over [S][S]
    u64 bal = __ballot(msk[gid] == 1);
    if ((tid & 63) == 0) mbits[(size_t)((gid >> 6) & 31) * 2048 + (gid >> 11)] = bal;
  } else {
    int i = (blk - 34560) * 256 + tid;  // 0..2047
    bqk[i] = (i < 1024) ? bq[i] : bk[i - 1024];
  }
}

// ---------------- fused QKV projection GEMM ----------------
// grid (64, 24). y<16: QK half — C_qk[M][2048] bf16 = Xc*Wqkt^T (+bqk), Q cols scaled.
// y>=16: V half — Vtg[bh][dk][S] bf16 transposed = Xv*Wvt^T (+bv).
// 128x128 tile, BK=32, 4 waves, global_load_lds staging (m97 structure).

__global__ __launch_bounds__(256) void qkv_gemm(const u16* __restrict__ Xc, const u16* __restrict__ Xv,
                                                const u16* __restrict__ Wqkt, const u16* __restrict__ Wvt,
                                                const float* __restrict__ bqk, const float* __restrict__ bvv,
                                                u16* __restrict__ QKb, u16* __restrict__ Vtg, float qscale) {
  __shared__ __align__(16) u16 As[128 * 32];
  __shared__ __align__(16) u16 Bs[128 * 32];
  const int tid = threadIdx.x;
  const int w = tid >> 6, lane = tid & 63, quad = lane >> 4, lc = lane & 15;
  const int K = 1024;
  const bool isV = blockIdx.y >= 16;
  const int m0 = blockIdx.x * 128;
  const int n0 = (isV ? (blockIdx.y - 16) : blockIdx.y) * 128;
  const u16* A  = isV ? Xv : Xc;
  const u16* Bt = isV ? Wvt : Wqkt;
  const float* bias = isV ? bvv : bqk;
  const int wrow = (w >> 1) * 64, wcol = (w & 1) * 64;
  const int srow = tid >> 2, sc = tid & 3;
  const u16* Ag = A + (size_t)(m0 + srow) * K + sc * 8;
  const u16* Bg = Bt + (size_t)(n0 + srow) * K + sc * 8;
  u16* Asw = As + w * 512;
  u16* Bsw = Bs + w * 512;

  f32x4 acc[4][4] = {};
  for (int k0 = 0; k0 < K; k0 += 32) {
    async16(Ag + k0, Asw);
    async16(Ag + k0 + (size_t)64 * K, Asw + 2048);
    async16(Bg + k0, Bsw);
    async16(Bg + k0 + (size_t)64 * K, Bsw + 2048);
    __syncthreads();
    bf16x8 af[4], bfr[4];
#pragma unroll
    for (int rt = 0; rt < 4; rt++) af[rt] = *(const bf16x8*)&As[(wrow + rt * 16 + lc) * 32 + quad * 8];
#pragma unroll
    for (int ct = 0; ct < 4; ct++) bfr[ct] = *(const bf16x8*)&Bs[(wcol + ct * 16 + lc) * 32 + quad * 8];
#pragma unroll
    for (int rt = 0; rt < 4; rt++)
#pragma unroll
      for (int ct = 0; ct < 4; ct++)
        acc[rt][ct] = __builtin_amdgcn_mfma_f32_16x16x32_bf16(af[rt], bfr[ct], acc[rt][ct], 0, 0, 0);
    __syncthreads();
  }
#pragma unroll
  for (int ct = 0; ct < 4; ct++) {
    int col = n0 + wcol + ct * 16 + lc;
    float bv = bias[col];
    float os = (!isV && col < 1024) ? qscale : 1.0f;
#pragma unroll
    for (int rt = 0; rt < 4; rt++) {
      if (isV) {
        int trow = m0 + wrow + rt * 16 + quad * 4;  // 4-aligned, never crosses 2048
        ushort4 pk;
        pk.x = f2bf(acc[rt][ct][0] + bv);
        pk.y = f2bf(acc[rt][ct][1] + bv);
        pk.z = f2bf(acc[rt][ct][2] + bv);
        pk.w = f2bf(acc[rt][ct][3] + bv);
        size_t off = ((size_t)(trow >> 11) * 1024 + col) * 2048 + (trow & 2047);
        *(ushort4*)(Vtg + off) = pk;
      } else {
#pragma unroll
        for (int r = 0; r < 4; r++) {
          int row = m0 + wrow + rt * 16 + quad * 4 + r;
          QKb[(size_t)row * 2048 + col] = f2bf((acc[rt][ct][r] + bv) * os);
        }
      }
    }
  }
}

// ---------------- flash attention v9 ----------------
// grid (S/128 = 16, B*H = 64) — exactly 4 blocks/CU. Block 256 = 4 waves,
// each wave owns 32 q-rows (2 strips of 16).
//
// v9 = R1's proven loop structure (NO #pragma unroll 2 — R2/R3/R4's ~400 MB
// WRITE_SIZE was scratch-spill traffic from the doubled live state) + the two
// cheap VALU cuts:
//  - Tbl AND-mask (v8, correctness-validated): bit-packed mbits expanded via
//    256-entry LDS table; 2 lookups + 8 ANDs per strip replaces ~32
//    bit-extract+cndmask VALU ops per strip.
//  - sacc zero-init folded into first MFMA's C operand (C=z).
// QK: bf16 [B*S][2048] (cols 0-1023 Q pre-scaled by 0.125*log2e, 1024-2047 K).
// Vt: bf16 [bh][dk][S]. PERMUTED K staging (v5) so post-exp P is lane-local
// and in PV A-fragment order. No max-subtraction. LDS 36 KB -> 4 blocks/CU.

__global__ __launch_bounds__(256, 4) void attn_kernel(const u16* __restrict__ QK, const u16* __restrict__ Vt,
                                                      const u64* __restrict__ mbits, u16* __restrict__ AO) {
  __shared__ __align__(16) u16 Ks[2][4096];
  __shared__ __align__(16) u16 Vs[2][4096];
  __shared__ uint4 Tbl[256];  // byte -> 4 AND-words (8 bf16 lanes of FF/00)
  const int S = 2048, D = 1024, QS = 2048;
  const int tid = threadIdx.x, w = tid >> 6, lane = tid & 63, quad = lane >> 4, lc = lane & 15;
  const int q0 = blockIdx.x * 128;
  const int b = blockIdx.y >> 4, h = blockIdx.y & 15;
  const size_t baseq = (size_t)b * S * QS + (size_t)h * 64;
  const size_t vbase = (size_t)blockIdx.y * 64 * S;
  const int sr = lane >> 3, gch = (lane & 7) ^ sr, lx = lc & 7;
  u16* Ksq = (u16*)Ks;  // 16 KB = 128 rows x 64 — Q pre-stage area

  // build mask-expansion table (mask-content independent): one entry per thread
  {
    unsigned bv = (unsigned)tid;
    uint4 e;
    e.x = mk2(bv, 0); e.y = mk2(bv, 2); e.z = mk2(bv, 4); e.w = mk2(bv, 6);
    Tbl[bv] = e;
  }

  // stage Q (wave w: rows q0+w*32 .. +31) into Ks region, chunk-XOR swizzled
#pragma unroll
  for (int i = 0; i < 4; i++) {
    const u16* g = QK + baseq + (size_t)(q0 + w * 32 + i * 8 + sr) * QS + gch * 8;
    async16(g, Ksq + w * 2048 + i * 512);
  }
  // permuted K source row for this lane: LDS slot s=16w+8i+sr holds key
  // 32(w&1)+4(w>>1) + 16i + 8(sr>>2) + (sr&3)  (see PV-fragment derivation)
  const int kperm = 32 * (w & 1) + 4 * (w >> 1) + 8 * (sr >> 2) + (sr & 3);
  const u16* Kg0 = QK + baseq + 1024 + (size_t)kperm * QS + gch * 8;
  const u16* Vg0 = Vt + vbase + (size_t)(w * 16 + sr) * S + gch * 8;
  __syncthreads();  // Q staged (also publishes Tbl)

  // Q fragments -> registers: aq[strip][ks]
  bf16x8 aq[2][2];
#pragma unroll
  for (int s = 0; s < 2; s++)
#pragma unroll
    for (int ks = 0; ks < 2; ks++)
      aq[s][ks] = *(const bf16x8*)&Ksq[w * 2048 + (s * 16 + lc) * 64 + (((ks * 4 + quad) ^ lx) << 3)];
  __syncthreads();  // all aq reads done before K staging overwrites region

  // prefetch tile 0 (K rows permuted: i=0 -> +0, i=1 -> +16 rows)
  async16(Kg0, Ks[0] + w * 1024);
  async16(Kg0 + (size_t)16 * QS, Ks[0] + w * 1024 + 512);
  async16(Vg0, Vs[0] + w * 1024);
  async16(Vg0 + (size_t)8 * S, Vs[0] + w * 1024 + 512);

  // mask word pointer: row = q0+w*32+lc (strip 0), +16 (strip 1); word = t0/64
  const u64* mptr = mbits + (size_t)(q0 + w * 32 + lc);
  const int sh8 = quad << 3;

  bf16x8 ones;
#pragma unroll
  for (int j = 0; j < 8; j++) ones[j] = (short)0x3F80;  // bf16 1.0

  const f32x4 z = {};  // hoisted zero quad: C operand for first MFMA of each chain
  f32x4 acco[2][4] = {};
  f32x4 accl[2] = {};

  for (int t0 = 0; t0 < S; t0 += 64) {
    const int cur = (t0 >> 6) & 1;
    __syncthreads();  // buf[cur] staged; all waves done with buf[cur^1]
    if (t0 + 64 < S) {
      const u16* Kg = Kg0 + (size_t)(t0 + 64) * QS;
      const u16* Vg = Vg0 + (t0 + 64);
      async16(Kg, Ks[cur ^ 1] + w * 1024);
      async16(Kg + (size_t)16 * QS, Ks[cur ^ 1] + w * 1024 + 512);
      async16(Vg, Vs[cur ^ 1] + w * 1024);
      async16(Vg + (size_t)8 * S, Vs[cur ^ 1] + w * 1024 + 512);
    }

    // mask words for this tile (issue early; consumed after QK)
    u64 mw0 = mptr[(size_t)(t0 >> 6) * 2048];
    u64 mw1 = mptr[(size_t)(t0 >> 6) * 2048 + 16];

    // swapped QK^T: sacc[s][ct][r] = S^T[key slot ct*16+quad*4+r][q=lc]
    // first MFMA of each chain takes C=z (no per-tile zero-init movs)
    f32x4 sacc[2][4];
    __builtin_amdgcn_s_setprio(1);
#pragma unroll
    for (int ct = 0; ct < 4; ct++) {  // ks = 0
      bf16x8 bk = *(const bf16x8*)&Ks[cur][(ct * 16 + lc) * 64 + ((quad ^ lx) << 3)];
      sacc[0][ct] = __builtin_amdgcn_mfma_f32_16x16x32_bf16(bk, aq[0][0], z, 0, 0, 0);
      sacc[1][ct] = __builtin_amdgcn_mfma_f32_16x16x32_bf16(bk, aq[1][0], z, 0, 0, 0);
    }
#pragma unroll
    for (int ct = 0; ct < 4; ct++) {  // ks = 1
      bf16x8 bk = *(const bf16x8*)&Ks[cur][(ct * 16 + lc) * 64 + (((4 + quad) ^ lx) << 3)];
      sacc[0][ct] = __builtin_amdgcn_mfma_f32_16x16x32_bf16(bk, aq[0][1], sacc[0][ct], 0, 0, 0);
      sacc[1][ct] = __builtin_amdgcn_mfma_f32_16x16x32_bf16(bk, aq[1][1], sacc[1][ct], 0, 0, 0);
    }
    __builtin_amdgcn_s_setprio(0);

    // per strip: table-lookup AND-masks; exp (unmasked) -> pack -> AND -> PV
#pragma unroll
    for (int s = 0; s < 2; s++) {
      const u64 mw = s ? mw1 : mw0;
      // f0 keys t0+8q+0..7 = byte q of lo; f1 keys t0+32+8q+0..7 = byte q of hi
      uint4 ma = Tbl[((unsigned)mw >> sh8) & 255u];
      uint4 mb = Tbl[((unsigned)(mw >> 32) >> sh8) & 255u];
      unsigned pu[4][4];
#pragma unroll
      for (int ct = 0; ct < 4; ct++)
#pragma unroll
        for (int r = 0; r < 4; r++)
          pu[ct][r] = __float_as_uint(fast_exp2(sacc[s][ct][r]));
      // frag[ks] keys 32ks+8quad+{0..7}; AND-words in key-sequential pair order
      union { unsigned u[4]; bf16x8 v; } f0, f1;
      f0.u[0] = pk_bf16(pu[0][1], pu[0][0]) & ma.x;
      f0.u[1] = pk_bf16(pu[0][3], pu[0][2]) & ma.y;
      f0.u[2] = pk_bf16(pu[2][1], pu[2][0]) & ma.z;
      f0.u[3] = pk_bf16(pu[2][3], pu[2][2]) & ma.w;
      f1.u[0] = pk_bf16(pu[1][1], pu[1][0]) & mb.x;
      f1.u[1] = pk_bf16(pu[1][3], pu[1][2]) & mb.y;
      f1.u[2] = pk_bf16(pu[3][1], pu[3][0]) & mb.z;
      f1.u[3] = pk_bf16(pu[3][3], pu[3][2]) & mb.w;

      __builtin_amdgcn_s_setprio(1);
#pragma unroll
      for (int ct = 0; ct < 4; ct++) {
        bf16x8 bv = *(const bf16x8*)&Vs[cur][(ct * 16 + lc) * 64 + ((quad ^ lx) << 3)];
        acco[s][ct] = __builtin_amdgcn_mfma_f32_16x16x32_bf16(f0.v, bv, acco[s][ct], 0, 0, 0);
      }
      accl[s] = __builtin_amdgcn_mfma_f32_16x16x32_bf16(f0.v, ones, accl[s], 0, 0, 0);
#pragma unroll
      for (int ct = 0; ct < 4; ct++) {
        bf16x8 bv = *(const bf16x8*)&Vs[cur][(ct * 16 + lc) * 64 + (((4 + quad) ^ lx) << 3)];
        acco[s][ct] = __builtin_amdgcn_mfma_f32_16x16x32_bf16(f1.v, bv, acco[s][ct], 0, 0, 0);
      }
      accl[s] = __builtin_amdgcn_mfma_f32_16x16x32_bf16(f1.v, ones, accl[s], 0, 0, 0);
      __builtin_amdgcn_s_setprio(0);
    }
  }

#pragma unroll
  for (int s = 0; s < 2; s++)
#pragma unroll
    for (int r = 0; r < 4; r++) {
      float inv = 1.0f / accl[s][r];
      size_t row = (size_t)b * S + q0 + w * 32 + s * 16 + quad * 4 + r;
#pragma unroll
      for (int ct = 0; ct < 4; ct++)
        AO[row * D + h * 64 + ct * 16 + lc] = f2bf(acco[s][ct][r] * inv);
    }
}

// ---------------- output projection GEMM (f32 out) ----------------

__global__ __launch_bounds__(256) void out_gemm(const u16* __restrict__ A, const u16* __restrict__ Bt,
                                                const float* __restrict__ bias, float* __restrict__ C) {
  __shared__ __align__(16) u16 As[128 * 32];
  __shared__ __align__(16) u16 Bs[128 * 32];
  const int tid = threadIdx.x;
  const int w = tid >> 6, lane = tid & 63, quad = lane >> 4, lc = lane & 15;
  const int K = 1024, N = 1024;
  const int m0 = blockIdx.x * 128, n0 = blockIdx.y * 128;
  const int wrow = (w >> 1) * 64, wcol = (w & 1) * 64;
  const int srow = tid >> 2, sc = tid & 3;
  const u16* Ag = A + (size_t)(m0 + srow) * K + sc * 8;
  const u16* Bg = Bt + (size_t)(n0 + srow) * K + sc * 8;
  u16* Asw = As + w * 512;
  u16* Bsw = Bs + w * 512;

  f32x4 acc[4][4] = {};
  for (int k0 = 0; k0 < K; k0 += 32) {
    async16(Ag + k0, Asw);
    async16(Ag + k0 + (size_t)64 * K, Asw + 2048);
    async16(Bg + k0, Bsw);
    async16(Bg + k0 + (size_t)64 * K, Bsw + 2048);
    __syncthreads();
    bf16x8 af[4], bfr[4];
#pragma unroll
    for (int rt = 0; rt < 4; rt++) af[rt] = *(const bf16x8*)&As[(wrow + rt * 16 + lc) * 32 + quad * 8];
#pragma unroll
    for (int ct = 0; ct < 4; ct++) bfr[ct] = *(const bf16x8*)&Bs[(wcol + ct * 16 + lc) * 32 + quad * 8];
#pragma unroll
    for (int rt = 0; rt < 4; rt++)
#pragma unroll
      for (int ct = 0; ct < 4; ct++)
        acc[rt][ct] = __builtin_amdgcn_mfma_f32_16x16x32_bf16(af[rt], bfr[ct], acc[rt][ct], 0, 0, 0);
    __syncthreads();
  }
#pragma unroll
  for (int ct = 0; ct < 4; ct++) {
    int col = n0 + wcol + ct * 16 + lc;
    float bv = bias[col];
#pragma unroll
    for (int rt = 0; rt < 4; rt++)
#pragma unroll
      for (int r = 0; r < 4; r++) {
        int row = m0 + wrow + rt * 16 + quad * 4 + r;
        C[(size_t)row * N + col] = acc[rt][ct][r] + bv;
      }
  }
}

// ---------------- launcher ----------------

extern "C" void kernel_launch(void* const* d_in, const int* in_sizes, int n_in,
                              void* d_out, int out_size, void* d_ws, size_t ws_size,
                              hipStream_t stream) {
  const int B = 4, S = 2048, D = 1024;
  const float* ctx = (const float*)d_in[0];
  const float* val = (const float*)d_in[1];
  const int*   msk = (const int*)d_in[2];
  const float* Wq  = (const float*)d_in[3];
  const float* bq  = (const float*)d_in[4];
  const float* Wk  = (const float*)d_in[5];
  const float* bk  = (const float*)d_in[6];
  const float* Wv  = (const float*)d_in[7];
  const float* bv  = (const float*)d_in[8];
  const float* Wo  = (const float*)d_in[9];
  const float* bo  = (const float*)d_in[10];
  float* out = (float*)d_out;

  char* ws = (char*)d_ws;
  size_t off = 0;
  auto alloc = [&](size_t sz) { void* p = ws + off; off += (sz + 255) & ~255ULL; return p; };
  const size_t NTOK = (size_t)B * S * D;  // 8388608
  u16* Xc  = (u16*)alloc(NTOK * 2);
  u16* Xv  = (u16*)alloc(NTOK * 2);
  u16* Wqt = (u16*)alloc((size_t)D * D * 2);   // Wqt/Wkt contiguous: fused B matrix
  u16* Wkt = (u16*)alloc((size_t)D * D * 2);
  u16* Wvt = (u16*)alloc((size_t)D * D * 2);
  u16* WoB = (u16*)alloc((size_t)D * D * 2);
  u16* QKb = (u16*)alloc(NTOK * 4);            // fused QK output [B*S][2048]
  u16* Vtg = (u16*)alloc(NTOK * 2);            // V transposed: [bh][dk][S]
  u64* mbits = (u64*)alloc((size_t)S * S / 8); // transposed: [word 0..31][row 0..2047]
  float* bqk = (float*)alloc(2048 * 4);
  u16* AO = Xc;  // alias: Xc dead after QKV GEMM (before attention runs)
  if (off > ws_size) return;  // workspace too small -> visible failure, no OOB

  const float qscale = 0.125f * 1.44269504088896f;  // 1/sqrt(DK) * log2(e)

  prep_kernel<<<34568, 256, 0, stream>>>(ctx, val, msk, Wq, Wk, Wv, Wo, bq, bk,
                                         Xc, Xv, Wqt, Wkt, Wvt, WoB, mbits, bqk);

  // fused Q|K|V projections (QK half N=2048 over Xc; V half N=1024 over Xv, transposed out)
  qkv_gemm<<<dim3(B * S / 128, 24), 256, 0, stream>>>(Xc, Xv, Wqt, Wvt, bqk, bv, QKb, Vtg, qscale);

  // attention
  attn_kernel<<<dim3(S / 128, B * 16), 256, 0, stream>>>(QKb, Vtg, mbits, AO);

  // output projection (f32 out)
  out_gemm<<<dim3(B * S / 128, D / 128), 256, 0, stream>>>(AO, WoB, bo, out);
}

// Round 6
// 332.911 us; speedup vs baseline: 1.3493x; 1.0239x over previous
//
#include <hip/hip_runtime.h>
#include <hip/hip_bf16.h>

#define DEVI __device__ __forceinline__

typedef __attribute__((ext_vector_type(8))) short bf16x8;
typedef __attribute__((ext_vector_type(4))) float f32x4;
typedef unsigned short u16;
typedef unsigned long long u64;

// ---------------- helpers ----------------

DEVI void async16(const void* g, const void* l) {
  __builtin_amdgcn_global_load_lds(
      (const __attribute__((address_space(1))) unsigned int*)g,
      (__attribute__((address_space(3))) unsigned int*)l, 16, 0, 0);
}

DEVI u16 f2bf(float x) {  // RNE f32->bf16 (finite inputs only)
  unsigned int u = __float_as_uint(x);
  return (u16)((u + 0x7fffu + ((u >> 16) & 1u)) >> 16);
}

DEVI float fast_exp2(float x) {
#if __has_builtin(__builtin_amdgcn_exp2f)
  return __builtin_amdgcn_exp2f(x);  // raw v_exp_f32, no libm wrapper
#else
  return exp2f(x);
#endif
}

// pack two f32 (trunc) into one u32 of 2x bf16: low=lo, high=hi
DEVI unsigned pk_bf16(unsigned hi, unsigned lo) {
#if __has_builtin(__builtin_amdgcn_perm)
  return __builtin_amdgcn_perm(hi, lo, 0x07060302u);  // v_perm_b32: {hi.b3,hi.b2,lo.b3,lo.b2}
#else
  return (hi & 0xffff0000u) | (lo >> 16);
#endif
}

// AND-word for 2 mask bits k,k+1 of byte b: low16 = bit k (0->keep), high16 = bit k+1
DEVI unsigned mk2(unsigned b, int k) {
  return ((((b >> k) & 1u) ? 0u : 0x0000FFFFu) | (((b >> (k + 1)) & 1u) ? 0u : 0xFFFF0000u));
}

// ---------------- fused prep kernel ----------------
// blocks [0,8192)       cast ctx -> Xc
// blocks [8192,16384)   cast val -> Xv
// blocks [16384,17408)  cast Wo  -> WoB
// blocks [17408,18176)  LDS-tiled transpose Wq/Wk/Wv -> Wqt/Wkt/Wvt (bf16)
// blocks [18176,34560)  mask bit-pack (TRANSPOSED: mbits[word][row]) — 512 KB total
// blocks [34560,34568)  bias concat bq|bk -> bqk

__global__ __launch_bounds__(256) void prep_kernel(
    const float* __restrict__ ctx, const float* __restrict__ val, const int* __restrict__ msk,
    const float* __restrict__ Wq, const float* __restrict__ Wk, const float* __restrict__ Wv,
    const float* __restrict__ Wo, const float* __restrict__ bq, const float* __restrict__ bk,
    u16* __restrict__ Xc, u16* __restrict__ Xv, u16* __restrict__ Wqt, u16* __restrict__ Wkt,
    u16* __restrict__ Wvt, u16* __restrict__ WoB, u64* __restrict__ mbits, float* __restrict__ bqk) {
  __shared__ float tile[64 * 69];
  const int blk = blockIdx.x, tid = threadIdx.x;
  if (blk < 16384) {
    const float* src = (blk < 8192) ? ctx : val;
    u16* dst = (blk < 8192) ? Xc : Xv;
    int i = (blk & 8191) * 256 + tid;
    float4 v = ((const float4*)src)[i];
    ushort4 o;
    o.x = f2bf(v.x); o.y = f2bf(v.y); o.z = f2bf(v.z); o.w = f2bf(v.w);
    ((ushort4*)dst)[i] = o;
  } else if (blk < 17408) {
    int i = (blk - 16384) * 256 + tid;
    float4 v = ((const float4*)Wo)[i];
    ushort4 o;
    o.x = f2bf(v.x); o.y = f2bf(v.y); o.z = f2bf(v.z); o.w = f2bf(v.w);
    ((ushort4*)WoB)[i] = o;
  } else if (blk < 18176) {
    // W [H=16][1024 d][64 k] -> Wt [h*64+k][1024 d]; 256 blocks per matrix
    int t = blk - 17408;
    int mat = t >> 8, r = t & 255, h = r >> 4, d0 = (r & 15) * 64;
    const float* Ws = (mat == 0) ? Wq : (mat == 1) ? Wk : Wv;
    u16* Wd = (mat == 0) ? Wqt : (mat == 1) ? Wkt : Wvt;
    const int dg = tid & 15, rg = tid >> 4;
#pragma unroll
    for (int i = 0; i < 4; i++) {
      int dr = rg + i * 16;
      float4 v = *(const float4*)&Ws[((size_t)(h * 1024 + d0 + dr)) * 64 + dg * 4];
      tile[dr * 69 + dg * 4 + 0] = v.x;
      tile[dr * 69 + dg * 4 + 1] = v.y;
      tile[dr * 69 + dg * 4 + 2] = v.z;
      tile[dr * 69 + dg * 4 + 3] = v.w;
    }
    __syncthreads();
#pragma unroll
    for (int i = 0; i < 4; i++) {
      int k = rg + i * 16;
      ushort4 o;
      o.x = f2bf(tile[(dg * 4 + 0) * 69 + k]);
      o.y = f2bf(tile[(dg * 4 + 1) * 69 + k]);
      o.z = f2bf(tile[(dg * 4 + 2) * 69 + k]);
      o.w = f2bf(tile[(dg * 4 + 3) * 69 + k]);
      *(ushort4*)&Wd[(size_t)(h * 64 + k) * 1024 + d0 + dg * 4] = o;
    }
  } else if (blk < 34560) {
    int gid = (blk - 18176) * 256 + tid;  // gid = row*2048 + col over [S][S]
    u64 bal = __ballot(msk[gid] == 1);
    if ((tid & 63) == 0) mbits[(size_t)((gid >> 6) & 31) * 2048 + (gid >> 11)] = bal;
  } else {
    int i = (blk - 34560) * 256 + tid;  // 0..2047
    bqk[i] = (i < 1024) ? bq[i] : bk[i - 1024];
  }
}

// ---------------- fused QKV projection GEMM ----------------
// grid (64, 24). y<16: QK half — C_qk[M][2048] bf16 = Xc*Wqkt^T (+bqk), Q cols scaled.
// y>=16: V half — Vtg[bh][dk][S] bf16 transposed = Xv*Wvt^T (+bv).
// 128x128 tile, BK=32, 4 waves, global_load_lds staging (m97 structure).

__global__ __launch_bounds__(256) void qkv_gemm(const u16* __restrict__ Xc, const u16* __restrict__ Xv,
                                                const u16* __restrict__ Wqkt, const u16* __restrict__ Wvt,
                                                const float* __restrict__ bqk, const float* __restrict__ bvv,
                                                u16* __restrict__ QKb, u16* __restrict__ Vtg, float qscale) {
  __shared__ __align__(16) u16 As[128 * 32];
  __shared__ __align__(16) u16 Bs[128 * 32];
  const int tid = threadIdx.x;
  const int w = tid >> 6, lane = tid & 63, quad = lane >> 4, lc = lane & 15;
  const int K = 1024;
  const bool isV = blockIdx.y >= 16;
  const int m0 = blockIdx.x * 128;
  const int n0 = (isV ? (blockIdx.y - 16) : blockIdx.y) * 128;
  const u16* A  = isV ? Xv : Xc;
  const u16* Bt = isV ? Wvt : Wqkt;
  const float* bias = isV ? bvv : bqk;
  const int wrow = (w >> 1) * 64, wcol = (w & 1) * 64;
  const int srow = tid >> 2, sc = tid & 3;
  const u16* Ag = A + (size_t)(m0 + srow) * K + sc * 8;
  const u16* Bg = Bt + (size_t)(n0 + srow) * K + sc * 8;
  u16* Asw = As + w * 512;
  u16* Bsw = Bs + w * 512;

  f32x4 acc[4][4] = {};
  for (int k0 = 0; k0 < K; k0 += 32) {
    async16(Ag + k0, Asw);
    async16(Ag + k0 + (size_t)64 * K, Asw + 2048);
    async16(Bg + k0, Bsw);
    async16(Bg + k0 + (size_t)64 * K, Bsw + 2048);
    __syncthreads();
    bf16x8 af[4], bfr[4];
#pragma unroll
    for (int rt = 0; rt < 4; rt++) af[rt] = *(const bf16x8*)&As[(wrow + rt * 16 + lc) * 32 + quad * 8];
#pragma unroll
    for (int ct = 0; ct < 4; ct++) bfr[ct] = *(const bf16x8*)&Bs[(wcol + ct * 16 + lc) * 32 + quad * 8];
#pragma unroll
    for (int rt = 0; rt < 4; rt++)
#pragma unroll
      for (int ct = 0; ct < 4; ct++)
        acc[rt][ct] = __builtin_amdgcn_mfma_f32_16x16x32_bf16(af[rt], bfr[ct], acc[rt][ct], 0, 0, 0);
    __syncthreads();
  }
#pragma unroll
  for (int ct = 0; ct < 4; ct++) {
    int col = n0 + wcol + ct * 16 + lc;
    float bv = bias[col];
    float os = (!isV && col < 1024) ? qscale : 1.0f;
#pragma unroll
    for (int rt = 0; rt < 4; rt++) {
      if (isV) {
        int trow = m0 + wrow + rt * 16 + quad * 4;  // 4-aligned, never crosses 2048
        ushort4 pk;
        pk.x = f2bf(acc[rt][ct][0] + bv);
        pk.y = f2bf(acc[rt][ct][1] + bv);
        pk.z = f2bf(acc[rt][ct][2] + bv);
        pk.w = f2bf(acc[rt][ct][3] + bv);
        size_t off = ((size_t)(trow >> 11) * 1024 + col) * 2048 + (trow & 2047);
        *(ushort4*)(Vtg + off) = pk;
      } else {
#pragma unroll
        for (int r = 0; r < 4; r++) {
          int row = m0 + wrow + rt * 16 + quad * 4 + r;
          QKb[(size_t)row * 2048 + col] = f2bf((acc[rt][ct][r] + bv) * os);
        }
      }
    }
  }
}

// ---------------- flash attention v10 ----------------
// grid (S/256 = 8, B*H = 64) = 512 blocks = 2/CU. Block 256 = 4 waves,
// each wave owns 64 q-rows (4 strips of 16) — doubles K/V LDS-read reuse.
// (R5 analysis: LDS pipe was the bottleneck at ~72 µs/CU — each wave re-reads
// the full K/V tile regardless of its q-row count, so rows/wave is the lever.)
//  - per tile: 2 rounds of {QK strips s,s+1 -> softmax+PV strips s,s+1}
//    keeps sacc at 32 VGPR (spill-safe; R4 lesson)
//  - V fragments hoisted to 8 regs once per tile, reused by all 4 strips
//    (compiler can't CSE LDS reads across async global_load_lds)
//  - Tbl AND-mask + C=z zero-fold as v9
// LDS: 32 KB SM (Q prestage, unioned with Ks/Vs dbuf) + 4 KB Tbl.
// __launch_bounds__(256,2): 2 waves/SIMD -> 256-VGPR budget (peak est ~240).

__global__ __launch_bounds__(256, 2) void attn_kernel(const u16* __restrict__ QK, const u16* __restrict__ Vt,
                                                      const u64* __restrict__ mbits, u16* __restrict__ AO) {
  __shared__ __align__(16) u16 SM[16384];  // [0,8K): Ks dbuf; [8K,16K): Vs dbuf; prologue: Q prestage (all 32 KB)
  __shared__ uint4 Tbl[256];  // byte -> 4 AND-words (8 bf16 lanes of FF/00)
  const int S = 2048, D = 1024, QS = 2048;
  const int tid = threadIdx.x, w = tid >> 6, lane = tid & 63, quad = lane >> 4, lc = lane & 15;
  const int q0 = blockIdx.x * 256;
  const int b = blockIdx.y >> 4, h = blockIdx.y & 15;
  const size_t baseq = (size_t)b * S * QS + (size_t)h * 64;
  const size_t vbase = (size_t)blockIdx.y * 64 * S;
  const int sr = lane >> 3, gch = (lane & 7) ^ sr, lx = lc & 7;

  // build mask-expansion table (mask-content independent): one entry per thread
  {
    unsigned bv = (unsigned)tid;
    uint4 e;
    e.x = mk2(bv, 0); e.y = mk2(bv, 2); e.z = mk2(bv, 4); e.w = mk2(bv, 6);
    Tbl[bv] = e;
  }

  // stage Q (wave w: rows q0+w*64 .. +63) into SM, chunk-XOR swizzled
#pragma unroll
  for (int i = 0; i < 8; i++) {
    const u16* g = QK + baseq + (size_t)(q0 + w * 64 + i * 8 + sr) * QS + gch * 8;
    async16(g, SM + w * 4096 + i * 512);
  }
  // permuted K source row (LDS slot s=16c+4q+r holds key 32(c&1)+8q+4(c>>1)+r)
  const int kperm = 32 * (w & 1) + 4 * (w >> 1) + 8 * (sr >> 2) + (sr & 3);
  const u16* Kg0 = QK + baseq + 1024 + (size_t)kperm * QS + gch * 8;
  const u16* Vg0 = Vt + vbase + (size_t)(w * 16 + sr) * S + gch * 8;
  __syncthreads();  // Q staged (also publishes Tbl)

  // Q fragments -> registers: aq[strip][ks]
  bf16x8 aq[4][2];
#pragma unroll
  for (int s = 0; s < 4; s++)
#pragma unroll
    for (int ks = 0; ks < 2; ks++)
      aq[s][ks] = *(const bf16x8*)&SM[w * 4096 + (s * 16 + lc) * 64 + (((ks * 4 + quad) ^ lx) << 3)];
  __syncthreads();  // all aq reads done before K/V staging overwrites region

  // prefetch tile 0 (K rows permuted: i=0 -> +0, i=1 -> +16 rows)
  async16(Kg0, SM + w * 1024);
  async16(Kg0 + (size_t)16 * QS, SM + w * 1024 + 512);
  async16(Vg0, SM + 8192 + w * 1024);
  async16(Vg0 + (size_t)8 * S, SM + 8192 + w * 1024 + 512);

  // mask word pointer: row = q0+w*64+s*16+lc; word = t0/64
  const u64* mptr = mbits + (size_t)(q0 + w * 64 + lc);
  const int sh8 = quad << 3;

  bf16x8 ones;
#pragma unroll
  for (int j = 0; j < 8; j++) ones[j] = (short)0x3F80;  // bf16 1.0

  const f32x4 z = {};  // hoisted zero quad: C operand for first MFMA of each chain
  f32x4 acco[4][4] = {};
  f32x4 accl[4] = {};

  for (int t0 = 0; t0 < S; t0 += 64) {
    const int cur = (t0 >> 6) & 1;
    const u16* Kc = SM + cur * 4096;
    const u16* Vc = SM + 8192 + cur * 4096;
    __syncthreads();  // buf[cur] staged; all waves done with buf[cur^1]
    if (t0 + 64 < S) {
      u16* Kn = SM + (cur ^ 1) * 4096;
      u16* Vn = SM + 8192 + (cur ^ 1) * 4096;
      const u16* Kg = Kg0 + (size_t)(t0 + 64) * QS;
      const u16* Vg = Vg0 + (t0 + 64);
      async16(Kg, Kn + w * 1024);
      async16(Kg + (size_t)16 * QS, Kn + w * 1024 + 512);
      async16(Vg, Vn + w * 1024);
      async16(Vg + (size_t)8 * S, Vn + w * 1024 + 512);
    }

    // mask words for this tile (issue early; consumed after QK)
    u64 mw0 = mptr[(size_t)(t0 >> 6) * 2048];
    u64 mw1 = mptr[(size_t)(t0 >> 6) * 2048 + 16];
    u64 mw2 = mptr[(size_t)(t0 >> 6) * 2048 + 32];
    u64 mw3 = mptr[(size_t)(t0 >> 6) * 2048 + 48];

    // hoist V fragments once; reused by all 4 strips (8 ds_read_b128)
    bf16x8 bv0[4], bv1[4];
#pragma unroll
    for (int ct = 0; ct < 4; ct++) {
      bv0[ct] = *(const bf16x8*)&Vc[(ct * 16 + lc) * 64 + ((quad ^ lx) << 3)];
      bv1[ct] = *(const bf16x8*)&Vc[(ct * 16 + lc) * 64 + (((4 + quad) ^ lx) << 3)];
    }

    // two rounds: {QK strips s0,s0+1 -> softmax+PV} — sacc stays 32 VGPR
#pragma unroll
    for (int rnd = 0; rnd < 2; rnd++) {
      const int s0 = rnd * 2;
      f32x4 sacc[2][4];
      __builtin_amdgcn_s_setprio(1);
#pragma unroll
      for (int ct = 0; ct < 4; ct++) {  // ks = 0 (C=z: no zero-init movs)
        bf16x8 bk = *(const bf16x8*)&Kc[(ct * 16 + lc) * 64 + ((quad ^ lx) << 3)];
        sacc[0][ct] = __builtin_amdgcn_mfma_f32_16x16x32_bf16(bk, aq[s0][0], z, 0, 0, 0);
        sacc[1][ct] = __builtin_amdgcn_mfma_f32_16x16x32_bf16(bk, aq[s0 + 1][0], z, 0, 0, 0);
      }
#pragma unroll
      for (int ct = 0; ct < 4; ct++) {  // ks = 1
        bf16x8 bk = *(const bf16x8*)&Kc[(ct * 16 + lc) * 64 + (((4 + quad) ^ lx) << 3)];
        sacc[0][ct] = __builtin_amdgcn_mfma_f32_16x16x32_bf16(bk, aq[s0][1], sacc[0][ct], 0, 0, 0);
        sacc[1][ct] = __builtin_amdgcn_mfma_f32_16x16x32_bf16(bk, aq[s0 + 1][1], sacc[1][ct], 0, 0, 0);
      }
      __builtin_amdgcn_s_setprio(0);

#pragma unroll
      for (int si = 0; si < 2; si++) {
        const int s = s0 + si;  // compile-time (both loops unrolled)
        const u64 mw = (s == 0) ? mw0 : (s == 1) ? mw1 : (s == 2) ? mw2 : mw3;
        uint4 ma = Tbl[((unsigned)mw >> sh8) & 255u];
        uint4 mb = Tbl[((unsigned)(mw >> 32) >> sh8) & 255u];
        unsigned pu[4][4];
#pragma unroll
        for (int ct = 0; ct < 4; ct++)
#pragma unroll
          for (int r = 0; r < 4; r++)
            pu[ct][r] = __float_as_uint(fast_exp2(sacc[si][ct][r]));
        // frag[ks] keys 32ks+8quad+{0..7}; AND-words in key-sequential pair order
        union { unsigned u[4]; bf16x8 v; } f0, f1;
        f0.u[0] = pk_bf16(pu[0][1], pu[0][0]) & ma.x;
        f0.u[1] = pk_bf16(pu[0][3], pu[0][2]) & ma.y;
        f0.u[2] = pk_bf16(pu[2][1], pu[2][0]) & ma.z;
        f0.u[3] = pk_bf16(pu[2][3], pu[2][2]) & ma.w;
        f1.u[0] = pk_bf16(pu[1][1], pu[1][0]) & mb.x;
        f1.u[1] = pk_bf16(pu[1][3], pu[1][2]) & mb.y;
        f1.u[2] = pk_bf16(pu[3][1], pu[3][0]) & mb.z;
        f1.u[3] = pk_bf16(pu[3][3], pu[3][2]) & mb.w;

        __builtin_amdgcn_s_setprio(1);
#pragma unroll
        for (int ct = 0; ct < 4; ct++)
          acco[s][ct] = __builtin_amdgcn_mfma_f32_16x16x32_bf16(f0.v, bv0[ct], acco[s][ct], 0, 0, 0);
        accl[s] = __builtin_amdgcn_mfma_f32_16x16x32_bf16(f0.v, ones, accl[s], 0, 0, 0);
#pragma unroll
        for (int ct = 0; ct < 4; ct++)
          acco[s][ct] = __builtin_amdgcn_mfma_f32_16x16x32_bf16(f1.v, bv1[ct], acco[s][ct], 0, 0, 0);
        accl[s] = __builtin_amdgcn_mfma_f32_16x16x32_bf16(f1.v, ones, accl[s], 0, 0, 0);
        __builtin_amdgcn_s_setprio(0);
      }
    }
  }

#pragma unroll
  for (int s = 0; s < 4; s++)
#pragma unroll
    for (int r = 0; r < 4; r++) {
      float inv = 1.0f / accl[s][r];
      size_t row = (size_t)b * S + q0 + w * 64 + s * 16 + quad * 4 + r;
#pragma unroll
      for (int ct = 0; ct < 4; ct++)
        AO[row * D + h * 64 + ct * 16 + lc] = f2bf(acco[s][ct][r] * inv);
    }
}

// ---------------- output projection GEMM (f32 out) ----------------

__global__ __launch_bounds__(256) void out_gemm(const u16* __restrict__ A, const u16* __restrict__ Bt,
                                                const float* __restrict__ bias, float* __restrict__ C) {
  __shared__ __align__(16) u16 As[128 * 32];
  __shared__ __align__(16) u16 Bs[128 * 32];
  const int tid = threadIdx.x;
  const int w = tid >> 6, lane = tid & 63, quad = lane >> 4, lc = lane & 15;
  const int K = 1024, N = 1024;
  const int m0 = blockIdx.x * 128, n0 = blockIdx.y * 128;
  const int wrow = (w >> 1) * 64, wcol = (w & 1) * 64;
  const int srow = tid >> 2, sc = tid & 3;
  const u16* Ag = A + (size_t)(m0 + srow) * K + sc * 8;
  const u16* Bg = Bt + (size_t)(n0 + srow) * K + sc * 8;
  u16* Asw = As + w * 512;
  u16* Bsw = Bs + w * 512;

  f32x4 acc[4][4] = {};
  for (int k0 = 0; k0 < K; k0 += 32) {
    async16(Ag + k0, Asw);
    async16(Ag + k0 + (size_t)64 * K, Asw + 2048);
    async16(Bg + k0, Bsw);
    async16(Bg + k0 + (size_t)64 * K, Bsw + 2048);
    __syncthreads();
    bf16x8 af[4], bfr[4];
#pragma unroll
    for (int rt = 0; rt < 4; rt++) af[rt] = *(const bf16x8*)&As[(wrow + rt * 16 + lc) * 32 + quad * 8];
#pragma unroll
    for (int ct = 0; ct < 4; ct++) bfr[ct] = *(const bf16x8*)&Bs[(wcol + ct * 16 + lc) * 32 + quad * 8];
#pragma unroll
    for (int rt = 0; rt < 4; rt++)
#pragma unroll
      for (int ct = 0; ct < 4; ct++)
        acc[rt][ct] = __builtin_amdgcn_mfma_f32_16x16x32_bf16(af[rt], bfr[ct], acc[rt][ct], 0, 0, 0);
    __syncthreads();
  }
#pragma unroll
  for (int ct = 0; ct < 4; ct++) {
    int col = n0 + wcol + ct * 16 + lc;
    float bv = bias[col];
#pragma unroll
    for (int rt = 0; rt < 4; rt++)
#pragma unroll
      for (int r = 0; r < 4; r++) {
        int row = m0 + wrow + rt * 16 + quad * 4 + r;
        C[(size_t)row * N + col] = acc[rt][ct][r] + bv;
      }
  }
}

// ---------------- launcher ----------------

extern "C" void kernel_launch(void* const* d_in, const int* in_sizes, int n_in,
                              void* d_out, int out_size, void* d_ws, size_t ws_size,
                              hipStream_t stream) {
  const int B = 4, S = 2048, D = 1024;
  const float* ctx = (const float*)d_in[0];
  const float* val = (const float*)d_in[1];
  const int*   msk = (const int*)d_in[2];
  const float* Wq  = (const float*)d_in[3];
  const float* bq  = (const float*)d_in[4];
  const float* Wk  = (const float*)d_in[5];
  const float* bk  = (const float*)d_in[6];
  const float* Wv  = (const float*)d_in[7];
  const float* bv  = (const float*)d_in[8];
  const float* Wo  = (const float*)d_in[9];
  const float* bo  = (const float*)d_in[10];
  float* out = (float*)d_out;

  char* ws = (char*)d_ws;
  size_t off = 0;
  auto alloc = [&](size_t sz) { void* p = ws + off; off += (sz + 255) & ~255ULL; return p; };
  const size_t NTOK = (size_t)B * S * D;  // 8388608
  u16* Xc  = (u16*)alloc(NTOK * 2);
  u16* Xv  = (u16*)alloc(NTOK * 2);
  u16* Wqt = (u16*)alloc((size_t)D * D * 2);   // Wqt/Wkt contiguous: fused B matrix
  u16* Wkt = (u16*)alloc((size_t)D * D * 2);
  u16* Wvt = (u16*)alloc((size_t)D * D * 2);
  u16* WoB = (u16*)alloc((size_t)D * D * 2);
  u16* QKb = (u16*)alloc(NTOK * 4);            // fused QK output [B*S][2048]
  u16* Vtg = (u16*)alloc(NTOK * 2);            // V transposed: [bh][dk][S]
  u64* mbits = (u64*)alloc((size_t)S * S / 8); // transposed: [word 0..31][row 0..2047]
  float* bqk = (float*)alloc(2048 * 4);
  u16* AO = Xc;  // alias: Xc dead after QKV GEMM (before attention runs)
  if (off > ws_size) return;  // workspace too small -> visible failure, no OOB

  const float qscale = 0.125f * 1.44269504088896f;  // 1/sqrt(DK) * log2(e)

  prep_kernel<<<34568, 256, 0, stream>>>(ctx, val, msk, Wq, Wk, Wv, Wo, bq, bk,
                                         Xc, Xv, Wqt, Wkt, Wvt, WoB, mbits, bqk);

  // fused Q|K|V projections (QK half N=2048 over Xc; V half N=1024 over Xv, transposed out)
  qkv_gemm<<<dim3(B * S / 128, 24), 256, 0, stream>>>(Xc, Xv, Wqt, Wvt, bqk, bv, QKb, Vtg, qscale);

  // attention (v10: 64 q-rows/wave, 2 blocks/CU)
  attn_kernel<<<dim3(S / 256, B * 16), 256, 0, stream>>>(QKb, Vtg, mbits, AO);

  // output projection (f32 out)
  out_gemm<<<dim3(B * S / 128, D / 128), 256, 0, stream>>>(AO, WoB, bo, out);
}

// Round 7
// 326.650 us; speedup vs baseline: 1.3752x; 1.0192x over previous
//
#include <hip/hip_runtime.h>
#include <hip/hip_bf16.h>

#define DEVI __device__ __forceinline__

typedef __attribute__((ext_vector_type(8))) short bf16x8;
typedef __attribute__((ext_vector_type(4))) float f32x4;
typedef unsigned short u16;
typedef unsigned long long u64;

// ---------------- helpers ----------------

DEVI void async16(const void* g, const void* l) {
  __builtin_amdgcn_global_load_lds(
      (const __attribute__((address_space(1))) unsigned int*)g,
      (__attribute__((address_space(3))) unsigned int*)l, 16, 0, 0);
}

DEVI u16 f2bf(float x) {  // RNE f32->bf16 (finite inputs only)
  unsigned int u = __float_as_uint(x);
  return (u16)((u + 0x7fffu + ((u >> 16) & 1u)) >> 16);
}

DEVI float fast_exp2(float x) {
#if __has_builtin(__builtin_amdgcn_exp2f)
  return __builtin_amdgcn_exp2f(x);  // raw v_exp_f32, no libm wrapper
#else
  return exp2f(x);
#endif
}

// pack two f32 (trunc) into one u32 of 2x bf16: low=lo, high=hi
DEVI unsigned pk_bf16(unsigned hi, unsigned lo) {
#if __has_builtin(__builtin_amdgcn_perm)
  return __builtin_amdgcn_perm(hi, lo, 0x07060302u);  // v_perm_b32: {hi.b3,hi.b2,lo.b3,lo.b2}
#else
  return (hi & 0xffff0000u) | (lo >> 16);
#endif
}

// AND-word for 2 mask bits k,k+1 of byte b: low16 = bit k (0->keep), high16 = bit k+1
DEVI unsigned mk2(unsigned b, int k) {
  return ((((b >> k) & 1u) ? 0u : 0x0000FFFFu) | (((b >> (k + 1)) & 1u) ? 0u : 0xFFFF0000u));
}

// ---------------- fused prep kernel ----------------
// blocks [0,8192)       cast ctx -> Xc
// blocks [8192,16384)   cast val -> Xv
// blocks [16384,17408)  cast Wo  -> WoB
// blocks [17408,18176)  LDS-tiled transpose Wq/Wk/Wv -> Wqt/Wkt/Wvt (bf16)
// blocks [18176,34560)  mask bit-pack (TRANSPOSED: mbits[word][row]) — 512 KB total
// blocks [34560,34568)  bias concat bq|bk -> bqk

__global__ __launch_bounds__(256) void prep_kernel(
    const float* __restrict__ ctx, const float* __restrict__ val, const int* __restrict__ msk,
    const float* __restrict__ Wq, const float* __restrict__ Wk, const float* __restrict__ Wv,
    const float* __restrict__ Wo, const float* __restrict__ bq, const float* __restrict__ bk,
    u16* __restrict__ Xc, u16* __restrict__ Xv, u16* __restrict__ Wqt, u16* __restrict__ Wkt,
    u16* __restrict__ Wvt, u16* __restrict__ WoB, u64* __restrict__ mbits, float* __restrict__ bqk) {
  __shared__ float tile[64 * 69];
  const int blk = blockIdx.x, tid = threadIdx.x;
  if (blk < 16384) {
    const float* src = (blk < 8192) ? ctx : val;
    u16* dst = (blk < 8192) ? Xc : Xv;
    int i = (blk & 8191) * 256 + tid;
    float4 v = ((const float4*)src)[i];
    ushort4 o;
    o.x = f2bf(v.x); o.y = f2bf(v.y); o.z = f2bf(v.z); o.w = f2bf(v.w);
    ((ushort4*)dst)[i] = o;
  } else if (blk < 17408) {
    int i = (blk - 16384) * 256 + tid;
    float4 v = ((const float4*)Wo)[i];
    ushort4 o;
    o.x = f2bf(v.x); o.y = f2bf(v.y); o.z = f2bf(v.z); o.w = f2bf(v.w);
    ((ushort4*)WoB)[i] = o;
  } else if (blk < 18176) {
    // W [H=16][1024 d][64 k] -> Wt [h*64+k][1024 d]; 256 blocks per matrix
    int t = blk - 17408;
    int mat = t >> 8, r = t & 255, h = r >> 4, d0 = (r & 15) * 64;
    const float* Ws = (mat == 0) ? Wq : (mat == 1) ? Wk : Wv;
    u16* Wd = (mat == 0) ? Wqt : (mat == 1) ? Wkt : Wvt;
    const int dg = tid & 15, rg = tid >> 4;
#pragma unroll
    for (int i = 0; i < 4; i++) {
      int dr = rg + i * 16;
      float4 v = *(const float4*)&Ws[((size_t)(h * 1024 + d0 + dr)) * 64 + dg * 4];
      tile[dr * 69 + dg * 4 + 0] = v.x;
      tile[dr * 69 + dg * 4 + 1] = v.y;
      tile[dr * 69 + dg * 4 + 2] = v.z;
      tile[dr * 69 + dg * 4 + 3] = v.w;
    }
    __syncthreads();
#pragma unroll
    for (int i = 0; i < 4; i++) {
      int k = rg + i * 16;
      ushort4 o;
      o.x = f2bf(tile[(dg * 4 + 0) * 69 + k]);
      o.y = f2bf(tile[(dg * 4 + 1) * 69 + k]);
      o.z = f2bf(tile[(dg * 4 + 2) * 69 + k]);
      o.w = f2bf(tile[(dg * 4 + 3) * 69 + k]);
      *(ushort4*)&Wd[(size_t)(h * 64 + k) * 1024 + d0 + dg * 4] = o;
    }
  } else if (blk < 34560) {
    int gid = (blk - 18176) * 256 + tid;  // gid = row*2048 + col over [S][S]
    u64 bal = __ballot(msk[gid] == 1);
    if ((tid & 63) == 0) mbits[(size_t)((gid >> 6) & 31) * 2048 + (gid >> 11)] = bal;
  } else {
    int i = (blk - 34560) * 256 + tid;  // 0..2047
    bqk[i] = (i < 1024) ? bq[i] : bk[i - 1024];
  }
}

// ---------------- fused QKV projection GEMM ----------------
// grid (64, 24). y<16: QK half — C_qk[M][2048] bf16 = Xc*Wqkt^T (+bqk), Q cols scaled.
// y>=16: V half — Vtg[bh][dk][S] bf16 transposed = Xv*Wvt^T (+bv).
// 128x128 tile, BK=32, 4 waves, global_load_lds staging (m97 structure).

__global__ __launch_bounds__(256) void qkv_gemm(const u16* __restrict__ Xc, const u16* __restrict__ Xv,
                                                const u16* __restrict__ Wqkt, const u16* __restrict__ Wvt,
                                                const float* __restrict__ bqk, const float* __restrict__ bvv,
                                                u16* __restrict__ QKb, u16* __restrict__ Vtg, float qscale) {
  __shared__ __align__(16) u16 As[128 * 32];
  __shared__ __align__(16) u16 Bs[128 * 32];
  const int tid = threadIdx.x;
  const int w = tid >> 6, lane = tid & 63, quad = lane >> 4, lc = lane & 15;
  const int K = 1024;
  const bool isV = blockIdx.y >= 16;
  const int m0 = blockIdx.x * 128;
  const int n0 = (isV ? (blockIdx.y - 16) : blockIdx.y) * 128;
  const u16* A  = isV ? Xv : Xc;
  const u16* Bt = isV ? Wvt : Wqkt;
  const float* bias = isV ? bvv : bqk;
  const int wrow = (w >> 1) * 64, wcol = (w & 1) * 64;
  const int srow = tid >> 2, sc = tid & 3;
  const u16* Ag = A + (size_t)(m0 + srow) * K + sc * 8;
  const u16* Bg = Bt + (size_t)(n0 + srow) * K + sc * 8;
  u16* Asw = As + w * 512;
  u16* Bsw = Bs + w * 512;

  f32x4 acc[4][4] = {};
  for (int k0 = 0; k0 < K; k0 += 32) {
    async16(Ag + k0, Asw);
    async16(Ag + k0 + (size_t)64 * K, Asw + 2048);
    async16(Bg + k0, Bsw);
    async16(Bg + k0 + (size_t)64 * K, Bsw + 2048);
    __syncthreads();
    bf16x8 af[4], bfr[4];
#pragma unroll
    for (int rt = 0; rt < 4; rt++) af[rt] = *(const bf16x8*)&As[(wrow + rt * 16 + lc) * 32 + quad * 8];
#pragma unroll
    for (int ct = 0; ct < 4; ct++) bfr[ct] = *(const bf16x8*)&Bs[(wcol + ct * 16 + lc) * 32 + quad * 8];
#pragma unroll
    for (int rt = 0; rt < 4; rt++)
#pragma unroll
      for (int ct = 0; ct < 4; ct++)
        acc[rt][ct] = __builtin_amdgcn_mfma_f32_16x16x32_bf16(af[rt], bfr[ct], acc[rt][ct], 0, 0, 0);
    __syncthreads();
  }
#pragma unroll
  for (int ct = 0; ct < 4; ct++) {
    int col = n0 + wcol + ct * 16 + lc;
    float bv = bias[col];
    float os = (!isV && col < 1024) ? qscale : 1.0f;
#pragma unroll
    for (int rt = 0; rt < 4; rt++) {
      if (isV) {
        int trow = m0 + wrow + rt * 16 + quad * 4;  // 4-aligned, never crosses 2048
        ushort4 pk;
        pk.x = f2bf(acc[rt][ct][0] + bv);
        pk.y = f2bf(acc[rt][ct][1] + bv);
        pk.z = f2bf(acc[rt][ct][2] + bv);
        pk.w = f2bf(acc[rt][ct][3] + bv);
        size_t off = ((size_t)(trow >> 11) * 1024 + col) * 2048 + (trow & 2047);
        *(ushort4*)(Vtg + off) = pk;
      } else {
#pragma unroll
        for (int r = 0; r < 4; r++) {
          int row = m0 + wrow + rt * 16 + quad * 4 + r;
          QKb[(size_t)row * 2048 + col] = f2bf((acc[rt][ct][r] + bv) * os);
        }
      }
    }
  }
}

// ---------------- flash attention v11 ----------------
// grid (S/256 = 8, B*H = 64) = 512 blocks = 2/CU. Block 256 = 4 waves,
// each wave owns 64 q-rows (4 strips of 16).
//
// v11 vs v10 (R6 null result: LDS-reads and occupancy both halved, perf
// identical -> bound by per-wave serial chain QK->SM->PV, pipes ping-pong):
//  - K fragments loaded ONCE per tile into regs (v10's 2 rounds re-read
//    identical fragments: 16 -> 8 ds_read_b128 per tile)
//  - ALL 32 QK MFMAs issued for all 4 strips first (sacc[4][4], 64 VGPR),
//    then per-strip softmax+PV: QK(s=2,3) issue fills sacc(s=0,1)->exp
//    latency; PV(s) MFMA execution overlaps softmax(s+1) VALU issue.
//  - V-hoist moved after QK phase so bk/bv live ranges don't overlap.
// VGPR est ~230 (2-wave budget 256). SPILL CANARY: WRITE_SIZE must stay
// ~16.4 MB (R4 lesson: spills show up as hundreds of MB of EA writes).

__global__ __launch_bounds__(256, 2) void attn_kernel(const u16* __restrict__ QK, const u16* __restrict__ Vt,
                                                      const u64* __restrict__ mbits, u16* __restrict__ AO) {
  __shared__ __align__(16) u16 SM[16384];  // [0,8K): Ks dbuf; [8K,16K): Vs dbuf; prologue: Q prestage (all 32 KB)
  __shared__ uint4 Tbl[256];  // byte -> 4 AND-words (8 bf16 lanes of FF/00)
  const int S = 2048, D = 1024, QS = 2048;
  const int tid = threadIdx.x, w = tid >> 6, lane = tid & 63, quad = lane >> 4, lc = lane & 15;
  const int q0 = blockIdx.x * 256;
  const int b = blockIdx.y >> 4, h = blockIdx.y & 15;
  const size_t baseq = (size_t)b * S * QS + (size_t)h * 64;
  const size_t vbase = (size_t)blockIdx.y * 64 * S;
  const int sr = lane >> 3, gch = (lane & 7) ^ sr, lx = lc & 7;

  // build mask-expansion table (mask-content independent): one entry per thread
  {
    unsigned bv = (unsigned)tid;
    uint4 e;
    e.x = mk2(bv, 0); e.y = mk2(bv, 2); e.z = mk2(bv, 4); e.w = mk2(bv, 6);
    Tbl[bv] = e;
  }

  // stage Q (wave w: rows q0+w*64 .. +63) into SM, chunk-XOR swizzled
#pragma unroll
  for (int i = 0; i < 8; i++) {
    const u16* g = QK + baseq + (size_t)(q0 + w * 64 + i * 8 + sr) * QS + gch * 8;
    async16(g, SM + w * 4096 + i * 512);
  }
  // permuted K source row (LDS slot s=16c+4q+r holds key 32(c&1)+8q+4(c>>1)+r)
  const int kperm = 32 * (w & 1) + 4 * (w >> 1) + 8 * (sr >> 2) + (sr & 3);
  const u16* Kg0 = QK + baseq + 1024 + (size_t)kperm * QS + gch * 8;
  const u16* Vg0 = Vt + vbase + (size_t)(w * 16 + sr) * S + gch * 8;
  __syncthreads();  // Q staged (also publishes Tbl)

  // Q fragments -> registers: aq[strip][ks]
  bf16x8 aq[4][2];
#pragma unroll
  for (int s = 0; s < 4; s++)
#pragma unroll
    for (int ks = 0; ks < 2; ks++)
      aq[s][ks] = *(const bf16x8*)&SM[w * 4096 + (s * 16 + lc) * 64 + (((ks * 4 + quad) ^ lx) << 3)];
  __syncthreads();  // all aq reads done before K/V staging overwrites region

  // prefetch tile 0 (K rows permuted: i=0 -> +0, i=1 -> +16 rows)
  async16(Kg0, SM + w * 1024);
  async16(Kg0 + (size_t)16 * QS, SM + w * 1024 + 512);
  async16(Vg0, SM + 8192 + w * 1024);
  async16(Vg0 + (size_t)8 * S, SM + 8192 + w * 1024 + 512);

  // mask word pointer: row = q0+w*64+s*16+lc; word = t0/64
  const u64* mptr = mbits + (size_t)(q0 + w * 64 + lc);
  const int sh8 = quad << 3;

  bf16x8 ones;
#pragma unroll
  for (int j = 0; j < 8; j++) ones[j] = (short)0x3F80;  // bf16 1.0

  const f32x4 z = {};  // hoisted zero quad: C operand for first MFMA of each chain
  f32x4 acco[4][4] = {};
  f32x4 accl[4] = {};

  for (int t0 = 0; t0 < S; t0 += 64) {
    const int cur = (t0 >> 6) & 1;
    const u16* Kc = SM + cur * 4096;
    const u16* Vc = SM + 8192 + cur * 4096;
    __syncthreads();  // buf[cur] staged; all waves done with buf[cur^1]
    if (t0 + 64 < S) {
      u16* Kn = SM + (cur ^ 1) * 4096;
      u16* Vn = SM + 8192 + (cur ^ 1) * 4096;
      const u16* Kg = Kg0 + (size_t)(t0 + 64) * QS;
      const u16* Vg = Vg0 + (t0 + 64);
      async16(Kg, Kn + w * 1024);
      async16(Kg + (size_t)16 * QS, Kn + w * 1024 + 512);
      async16(Vg, Vn + w * 1024);
      async16(Vg + (size_t)8 * S, Vn + w * 1024 + 512);
    }

    // mask words for this tile (issue early; consumed after QK)
    u64 mw0 = mptr[(size_t)(t0 >> 6) * 2048];
    u64 mw1 = mptr[(size_t)(t0 >> 6) * 2048 + 16];
    u64 mw2 = mptr[(size_t)(t0 >> 6) * 2048 + 32];
    u64 mw3 = mptr[(size_t)(t0 >> 6) * 2048 + 48];

    // ---- phase 1: K fragments once, then ALL QK MFMAs (4 strips) ----
    bf16x8 bk0[4], bk1[4];
#pragma unroll
    for (int ct = 0; ct < 4; ct++) {
      bk0[ct] = *(const bf16x8*)&Kc[(ct * 16 + lc) * 64 + ((quad ^ lx) << 3)];
      bk1[ct] = *(const bf16x8*)&Kc[(ct * 16 + lc) * 64 + (((4 + quad) ^ lx) << 3)];
    }
    f32x4 sacc[4][4];
    __builtin_amdgcn_s_setprio(1);
#pragma unroll
    for (int s = 0; s < 4; s++)
#pragma unroll
      for (int ct = 0; ct < 4; ct++)
        sacc[s][ct] = __builtin_amdgcn_mfma_f32_16x16x32_bf16(bk0[ct], aq[s][0], z, 0, 0, 0);
#pragma unroll
    for (int s = 0; s < 4; s++)
#pragma unroll
      for (int ct = 0; ct < 4; ct++)
        sacc[s][ct] = __builtin_amdgcn_mfma_f32_16x16x32_bf16(bk1[ct], aq[s][1], sacc[s][ct], 0, 0, 0);
    __builtin_amdgcn_s_setprio(0);

    // ---- phase 2: V fragments once; per-strip softmax+PV ----
    bf16x8 bv0[4], bv1[4];
#pragma unroll
    for (int ct = 0; ct < 4; ct++) {
      bv0[ct] = *(const bf16x8*)&Vc[(ct * 16 + lc) * 64 + ((quad ^ lx) << 3)];
      bv1[ct] = *(const bf16x8*)&Vc[(ct * 16 + lc) * 64 + (((4 + quad) ^ lx) << 3)];
    }

#pragma unroll
    for (int s = 0; s < 4; s++) {
      const u64 mw = (s == 0) ? mw0 : (s == 1) ? mw1 : (s == 2) ? mw2 : mw3;
      uint4 ma = Tbl[((unsigned)mw >> sh8) & 255u];
      uint4 mb = Tbl[((unsigned)(mw >> 32) >> sh8) & 255u];
      unsigned pu[4][4];
#pragma unroll
      for (int ct = 0; ct < 4; ct++)
#pragma unroll
        for (int r = 0; r < 4; r++)
          pu[ct][r] = __float_as_uint(fast_exp2(sacc[s][ct][r]));
      // frag[ks] keys 32ks+8quad+{0..7}; AND-words in key-sequential pair order
      union { unsigned u[4]; bf16x8 v; } f0, f1;
      f0.u[0] = pk_bf16(pu[0][1], pu[0][0]) & ma.x;
      f0.u[1] = pk_bf16(pu[0][3], pu[0][2]) & ma.y;
      f0.u[2] = pk_bf16(pu[2][1], pu[2][0]) & ma.z;
      f0.u[3] = pk_bf16(pu[2][3], pu[2][2]) & ma.w;
      f1.u[0] = pk_bf16(pu[1][1], pu[1][0]) & mb.x;
      f1.u[1] = pk_bf16(pu[1][3], pu[1][2]) & mb.y;
      f1.u[2] = pk_bf16(pu[3][1], pu[3][0]) & mb.z;
      f1.u[3] = pk_bf16(pu[3][3], pu[3][2]) & mb.w;

      __builtin_amdgcn_s_setprio(1);
#pragma unroll
      for (int ct = 0; ct < 4; ct++)
        acco[s][ct] = __builtin_amdgcn_mfma_f32_16x16x32_bf16(f0.v, bv0[ct], acco[s][ct], 0, 0, 0);
      accl[s] = __builtin_amdgcn_mfma_f32_16x16x32_bf16(f0.v, ones, accl[s], 0, 0, 0);
#pragma unroll
      for (int ct = 0; ct < 4; ct++)
        acco[s][ct] = __builtin_amdgcn_mfma_f32_16x16x32_bf16(f1.v, bv1[ct], acco[s][ct], 0, 0, 0);
      accl[s] = __builtin_amdgcn_mfma_f32_16x16x32_bf16(f1.v, ones, accl[s], 0, 0, 0);
      __builtin_amdgcn_s_setprio(0);
    }
  }

#pragma unroll
  for (int s = 0; s < 4; s++)
#pragma unroll
    for (int r = 0; r < 4; r++) {
      float inv = 1.0f / accl[s][r];
      size_t row = (size_t)b * S + q0 + w * 64 + s * 16 + quad * 4 + r;
#pragma unroll
      for (int ct = 0; ct < 4; ct++)
        AO[row * D + h * 64 + ct * 16 + lc] = f2bf(acco[s][ct][r] * inv);
    }
}

// ---------------- output projection GEMM (f32 out) ----------------

__global__ __launch_bounds__(256) void out_gemm(const u16* __restrict__ A, const u16* __restrict__ Bt,
                                                const float* __restrict__ bias, float* __restrict__ C) {
  __shared__ __align__(16) u16 As[128 * 32];
  __shared__ __align__(16) u16 Bs[128 * 32];
  const int tid = threadIdx.x;
  const int w = tid >> 6, lane = tid & 63, quad = lane >> 4, lc = lane & 15;
  const int K = 1024, N = 1024;
  const int m0 = blockIdx.x * 128, n0 = blockIdx.y * 128;
  const int wrow = (w >> 1) * 64, wcol = (w & 1) * 64;
  const int srow = tid >> 2, sc = tid & 3;
  const u16* Ag = A + (size_t)(m0 + srow) * K + sc * 8;
  const u16* Bg = Bt + (size_t)(n0 + srow) * K + sc * 8;
  u16* Asw = As + w * 512;
  u16* Bsw = Bs + w * 512;

  f32x4 acc[4][4] = {};
  for (int k0 = 0; k0 < K; k0 += 32) {
    async16(Ag + k0, Asw);
    async16(Ag + k0 + (size_t)64 * K, Asw + 2048);
    async16(Bg + k0, Bsw);
    async16(Bg + k0 + (size_t)64 * K, Bsw + 2048);
    __syncthreads();
    bf16x8 af[4], bfr[4];
#pragma unroll
    for (int rt = 0; rt < 4; rt++) af[rt] = *(const bf16x8*)&As[(wrow + rt * 16 + lc) * 32 + quad * 8];
#pragma unroll
    for (int ct = 0; ct < 4; ct++) bfr[ct] = *(const bf16x8*)&Bs[(wcol + ct * 16 + lc) * 32 + quad * 8];
#pragma unroll
    for (int rt = 0; rt < 4; rt++)
#pragma unroll
      for (int ct = 0; ct < 4; ct++)
        acc[rt][ct] = __builtin_amdgcn_mfma_f32_16x16x32_bf16(af[rt], bfr[ct], acc[rt][ct], 0, 0, 0);
    __syncthreads();
  }
#pragma unroll
  for (int ct = 0; ct < 4; ct++) {
    int col = n0 + wcol + ct * 16 + lc;
    float bv = bias[col];
#pragma unroll
    for (int rt = 0; rt < 4; rt++)
#pragma unroll
      for (int r = 0; r < 4; r++) {
        int row = m0 + wrow + rt * 16 + quad * 4 + r;
        C[(size_t)row * N + col] = acc[rt][ct][r] + bv;
      }
  }
}

// ---------------- launcher ----------------

extern "C" void kernel_launch(void* const* d_in, const int* in_sizes, int n_in,
                              void* d_out, int out_size, void* d_ws, size_t ws_size,
                              hipStream_t stream) {
  const int B = 4, S = 2048, D = 1024;
  const float* ctx = (const float*)d_in[0];
  const float* val = (const float*)d_in[1];
  const int*   msk = (const int*)d_in[2];
  const float* Wq  = (const float*)d_in[3];
  const float* bq  = (const float*)d_in[4];
  const float* Wk  = (const float*)d_in[5];
  const float* bk  = (const float*)d_in[6];
  const float* Wv  = (const float*)d_in[7];
  const float* bv  = (const float*)d_in[8];
  const float* Wo  = (const float*)d_in[9];
  const float* bo  = (const float*)d_in[10];
  float* out = (float*)d_out;

  char* ws = (char*)d_ws;
  size_t off = 0;
  auto alloc = [&](size_t sz) { void* p = ws + off; off += (sz + 255) & ~255ULL; return p; };
  const size_t NTOK = (size_t)B * S * D;  // 8388608
  u16* Xc  = (u16*)alloc(NTOK * 2);
  u16* Xv  = (u16*)alloc(NTOK * 2);
  u16* Wqt = (u16*)alloc((size_t)D * D * 2);   // Wqt/Wkt contiguous: fused B matrix
  u16* Wkt = (u16*)alloc((size_t)D * D * 2);
  u16* Wvt = (u16*)alloc((size_t)D * D * 2);
  u16* WoB = (u16*)alloc((size_t)D * D * 2);
  u16* QKb = (u16*)alloc(NTOK * 4);            // fused QK output [B*S][2048]
  u16* Vtg = (u16*)alloc(NTOK * 2);            // V transposed: [bh][dk][S]
  u64* mbits = (u64*)alloc((size_t)S * S / 8); // transposed: [word 0..31][row 0..2047]
  float* bqk = (float*)alloc(2048 * 4);
  u16* AO = Xc;  // alias: Xc dead after QKV GEMM (before attention runs)
  if (off > ws_size) return;  // workspace too small -> visible failure, no OOB

  const float qscale = 0.125f * 1.44269504088896f;  // 1/sqrt(DK) * log2(e)

  prep_kernel<<<34568, 256, 0, stream>>>(ctx, val, msk, Wq, Wk, Wv, Wo, bq, bk,
                                         Xc, Xv, Wqt, Wkt, Wvt, WoB, mbits, bqk);

  // fused Q|K|V projections (QK half N=2048 over Xc; V half N=1024 over Xv, transposed out)
  qkv_gemm<<<dim3(B * S / 128, 24), 256, 0, stream>>>(Xc, Xv, Wqt, Wvt, bqk, bv, QKb, Vtg, qscale);

  // attention (v11: merged QK phase, 64 q-rows/wave, 2 blocks/CU)
  attn_kernel<<<dim3(S / 256, B * 16), 256, 0, stream>>>(QKb, Vtg, mbits, AO);

  // output projection (f32 out)
  out_gemm<<<dim3(B * S / 128, D / 128), 256, 0, stream>>>(AO, WoB, bo, out);
}

// Round 8
// 318.675 us; speedup vs baseline: 1.4096x; 1.0250x over previous
//
#include <hip/hip_runtime.h>
#include <hip/hip_bf16.h>

#define DEVI __device__ __forceinline__

typedef __attribute__((ext_vector_type(8))) short bf16x8;
typedef __attribute__((ext_vector_type(4))) float f32x4;
typedef unsigned short u16;
typedef unsigned long long u64;

// ---------------- helpers ----------------

DEVI void async16(const void* g, const void* l) {
  __builtin_amdgcn_global_load_lds(
      (const __attribute__((address_space(1))) unsigned int*)g,
      (__attribute__((address_space(3))) unsigned int*)l, 16, 0, 0);
}

DEVI u16 f2bf(float x) {  // RNE f32->bf16 (finite inputs only)
  unsigned int u = __float_as_uint(x);
  return (u16)((u + 0x7fffu + ((u >> 16) & 1u)) >> 16);
}

DEVI float fast_exp2(float x) {
#if __has_builtin(__builtin_amdgcn_exp2f)
  return __builtin_amdgcn_exp2f(x);  // raw v_exp_f32, no libm wrapper
#else
  return exp2f(x);
#endif
}

// pack two f32 (trunc) into one u32 of 2x bf16: low=lo, high=hi
DEVI unsigned pk_bf16(unsigned hi, unsigned lo) {
#if __has_builtin(__builtin_amdgcn_perm)
  return __builtin_amdgcn_perm(hi, lo, 0x07060302u);  // v_perm_b32: {hi.b3,hi.b2,lo.b3,lo.b2}
#else
  return (hi & 0xffff0000u) | (lo >> 16);
#endif
}

// AND-word for 2 mask bits k,k+1 of byte b: low16 = bit k (0->keep), high16 = bit k+1
DEVI unsigned mk2(unsigned b, int k) {
  return ((((b >> k) & 1u) ? 0u : 0x0000FFFFu) | (((b >> (k + 1)) & 1u) ? 0u : 0xFFFF0000u));
}

// ---------------- fused prep kernel ----------------
// blocks [0,8192)       cast ctx -> Xc
// blocks [8192,16384)   cast val -> Xv
// blocks [16384,17408)  cast Wo  -> WoB
// blocks [17408,18176)  LDS-tiled transpose Wq/Wk/Wv -> Wqt/Wkt/Wvt (bf16)
// blocks [18176,34560)  mask bit-pack (TRANSPOSED: mbits[word][row]) — 512 KB total
// blocks [34560,34568)  bias concat bq|bk -> bqk

__global__ __launch_bounds__(256) void prep_kernel(
    const float* __restrict__ ctx, const float* __restrict__ val, const int* __restrict__ msk,
    const float* __restrict__ Wq, const float* __restrict__ Wk, const float* __restrict__ Wv,
    const float* __restrict__ Wo, const float* __restrict__ bq, const float* __restrict__ bk,
    u16* __restrict__ Xc, u16* __restrict__ Xv, u16* __restrict__ Wqt, u16* __restrict__ Wkt,
    u16* __restrict__ Wvt, u16* __restrict__ WoB, u64* __restrict__ mbits, float* __restrict__ bqk) {
  __shared__ float tile[64 * 69];
  const int blk = blockIdx.x, tid = threadIdx.x;
  if (blk < 16384) {
    const float* src = (blk < 8192) ? ctx : val;
    u16* dst = (blk < 8192) ? Xc : Xv;
    int i = (blk & 8191) * 256 + tid;
    float4 v = ((const float4*)src)[i];
    ushort4 o;
    o.x = f2bf(v.x); o.y = f2bf(v.y); o.z = f2bf(v.z); o.w = f2bf(v.w);
    ((ushort4*)dst)[i] = o;
  } else if (blk < 17408) {
    int i = (blk - 16384) * 256 + tid;
    float4 v = ((const float4*)Wo)[i];
    ushort4 o;
    o.x = f2bf(v.x); o.y = f2bf(v.y); o.z = f2bf(v.z); o.w = f2bf(v.w);
    ((ushort4*)WoB)[i] = o;
  } else if (blk < 18176) {
    // W [H=16][1024 d][64 k] -> Wt [h*64+k][1024 d]; 256 blocks per matrix
    int t = blk - 17408;
    int mat = t >> 8, r = t & 255, h = r >> 4, d0 = (r & 15) * 64;
    const float* Ws = (mat == 0) ? Wq : (mat == 1) ? Wk : Wv;
    u16* Wd = (mat == 0) ? Wqt : (mat == 1) ? Wkt : Wvt;
    const int dg = tid & 15, rg = tid >> 4;
#pragma unroll
    for (int i = 0; i < 4; i++) {
      int dr = rg + i * 16;
      float4 v = *(const float4*)&Ws[((size_t)(h * 1024 + d0 + dr)) * 64 + dg * 4];
      tile[dr * 69 + dg * 4 + 0] = v.x;
      tile[dr * 69 + dg * 4 + 1] = v.y;
      tile[dr * 69 + dg * 4 + 2] = v.z;
      tile[dr * 69 + dg * 4 + 3] = v.w;
    }
    __syncthreads();
#pragma unroll
    for (int i = 0; i < 4; i++) {
      int k = rg + i * 16;
      ushort4 o;
      o.x = f2bf(tile[(dg * 4 + 0) * 69 + k]);
      o.y = f2bf(tile[(dg * 4 + 1) * 69 + k]);
      o.z = f2bf(tile[(dg * 4 + 2) * 69 + k]);
      o.w = f2bf(tile[(dg * 4 + 3) * 69 + k]);
      *(ushort4*)&Wd[(size_t)(h * 64 + k) * 1024 + d0 + dg * 4] = o;
    }
  } else if (blk < 34560) {
    int gid = (blk - 18176) * 256 + tid;  // gid = row*2048 + col over [S][S]
    u64 bal = __ballot(msk[gid] == 1);
    if ((tid & 63) == 0) mbits[(size_t)((gid >> 6) & 31) * 2048 + (gid >> 11)] = bal;
  } else {
    int i = (blk - 34560) * 256 + tid;  // 0..2047
    bqk[i] = (i < 1024) ? bq[i] : bk[i - 1024];
  }
}

// ---------------- fused QKV projection GEMM ----------------
// grid (64, 24). y<16: QK half — C_qk[M][2048] bf16 = Xc*Wqkt^T (+bqk), Q cols scaled.
// y>=16: V half — Vtg[bh][dk][S] bf16 transposed = Xv*Wvt^T (+bv).
// 128x128 tile, BK=32, 4 waves.
// R8: T3-minimum single-barrier LDS double-buffer (attn-validated pattern):
//   barrier -> stage NEXT k-step into buf^1 -> ds_read+MFMA buf.
// Staging latency hides under the 16-MFMA phase (drained at next barrier);
// barriers per K-step 2 -> 1. (Old shape exposed a vmcnt(0) drain with zero
// compute in flight every step: MfmaUtil 21%, VALU 14%, HBM 13% = latency-bound.)
// LDS 32 KB -> still 4 blocks/CU (VGPR-limited).

__global__ __launch_bounds__(256) void qkv_gemm(const u16* __restrict__ Xc, const u16* __restrict__ Xv,
                                                const u16* __restrict__ Wqkt, const u16* __restrict__ Wvt,
                                                const float* __restrict__ bqk, const float* __restrict__ bvv,
                                                u16* __restrict__ QKb, u16* __restrict__ Vtg, float qscale) {
  __shared__ __align__(16) u16 As[2][128 * 32];
  __shared__ __align__(16) u16 Bs[2][128 * 32];
  const int tid = threadIdx.x;
  const int w = tid >> 6, lane = tid & 63, quad = lane >> 4, lc = lane & 15;
  const int K = 1024;
  const bool isV = blockIdx.y >= 16;
  const int m0 = blockIdx.x * 128;
  const int n0 = (isV ? (blockIdx.y - 16) : blockIdx.y) * 128;
  const u16* A  = isV ? Xv : Xc;
  const u16* Bt = isV ? Wvt : Wqkt;
  const float* bias = isV ? bvv : bqk;
  const int wrow = (w >> 1) * 64, wcol = (w & 1) * 64;
  const int srow = tid >> 2, sc = tid & 3;
  const u16* Ag = A + (size_t)(m0 + srow) * K + sc * 8;
  const u16* Bg = Bt + (size_t)(n0 + srow) * K + sc * 8;

  // prologue: stage k0=0 into buf 0
  async16(Ag, As[0] + w * 512);
  async16(Ag + (size_t)64 * K, As[0] + w * 512 + 2048);
  async16(Bg, Bs[0] + w * 512);
  async16(Bg + (size_t)64 * K, Bs[0] + w * 512 + 2048);

  f32x4 acc[4][4] = {};
  for (int k0 = 0; k0 < K; k0 += 32) {
    const int cur = (k0 >> 5) & 1;
    __syncthreads();  // buf[cur] staged (compiler drains vmcnt/lgkm here)
    if (k0 + 32 < K) {  // stage next k-step into buf^1; flies under MFMA below
      async16(Ag + k0 + 32, As[cur ^ 1] + w * 512);
      async16(Ag + k0 + 32 + (size_t)64 * K, As[cur ^ 1] + w * 512 + 2048);
      async16(Bg + k0 + 32, Bs[cur ^ 1] + w * 512);
      async16(Bg + k0 + 32 + (size_t)64 * K, Bs[cur ^ 1] + w * 512 + 2048);
    }
    bf16x8 af[4], bfr[4];
#pragma unroll
    for (int rt = 0; rt < 4; rt++) af[rt] = *(const bf16x8*)&As[cur][(wrow + rt * 16 + lc) * 32 + quad * 8];
#pragma unroll
    for (int ct = 0; ct < 4; ct++) bfr[ct] = *(const bf16x8*)&Bs[cur][(wcol + ct * 16 + lc) * 32 + quad * 8];
#pragma unroll
    for (int rt = 0; rt < 4; rt++)
#pragma unroll
      for (int ct = 0; ct < 4; ct++)
        acc[rt][ct] = __builtin_amdgcn_mfma_f32_16x16x32_bf16(af[rt], bfr[ct], acc[rt][ct], 0, 0, 0);
  }
#pragma unroll
  for (int ct = 0; ct < 4; ct++) {
    int col = n0 + wcol + ct * 16 + lc;
    float bv = bias[col];
    float os = (!isV && col < 1024) ? qscale : 1.0f;
#pragma unroll
    for (int rt = 0; rt < 4; rt++) {
      if (isV) {
        int trow = m0 + wrow + rt * 16 + quad * 4;  // 4-aligned, never crosses 2048
        ushort4 pk;
        pk.x = f2bf(acc[rt][ct][0] + bv);
        pk.y = f2bf(acc[rt][ct][1] + bv);
        pk.z = f2bf(acc[rt][ct][2] + bv);
        pk.w = f2bf(acc[rt][ct][3] + bv);
        size_t off = ((size_t)(trow >> 11) * 1024 + col) * 2048 + (trow & 2047);
        *(ushort4*)(Vtg + off) = pk;
      } else {
#pragma unroll
        for (int r = 0; r < 4; r++) {
          int row = m0 + wrow + rt * 16 + quad * 4 + r;
          QKb[(size_t)row * 2048 + col] = f2bf((acc[rt][ct][r] + bv) * os);
        }
      }
    }
  }
}

// ---------------- flash attention v11 ----------------
// grid (S/256 = 8, B*H = 64) = 512 blocks = 2/CU. Block 256 = 4 waves,
// each wave owns 64 q-rows (4 strips of 16).
// (see R7 notes: merged QK phase for all 4 strips, K/V fragments hoisted,
// Tbl AND-mask, C=z zero-fold, WRITE_SIZE spill canary.)

__global__ __launch_bounds__(256, 2) void attn_kernel(const u16* __restrict__ QK, const u16* __restrict__ Vt,
                                                      const u64* __restrict__ mbits, u16* __restrict__ AO) {
  __shared__ __align__(16) u16 SM[16384];  // [0,8K): Ks dbuf; [8K,16K): Vs dbuf; prologue: Q prestage (all 32 KB)
  __shared__ uint4 Tbl[256];  // byte -> 4 AND-words (8 bf16 lanes of FF/00)
  const int S = 2048, D = 1024, QS = 2048;
  const int tid = threadIdx.x, w = tid >> 6, lane = tid & 63, quad = lane >> 4, lc = lane & 15;
  const int q0 = blockIdx.x * 256;
  const int b = blockIdx.y >> 4, h = blockIdx.y & 15;
  const size_t baseq = (size_t)b * S * QS + (size_t)h * 64;
  const size_t vbase = (size_t)blockIdx.y * 64 * S;
  const int sr = lane >> 3, gch = (lane & 7) ^ sr, lx = lc & 7;

  // build mask-expansion table (mask-content independent): one entry per thread
  {
    unsigned bv = (unsigned)tid;
    uint4 e;
    e.x = mk2(bv, 0); e.y = mk2(bv, 2); e.z = mk2(bv, 4); e.w = mk2(bv, 6);
    Tbl[bv] = e;
  }

  // stage Q (wave w: rows q0+w*64 .. +63) into SM, chunk-XOR swizzled
#pragma unroll
  for (int i = 0; i < 8; i++) {
    const u16* g = QK + baseq + (size_t)(q0 + w * 64 + i * 8 + sr) * QS + gch * 8;
    async16(g, SM + w * 4096 + i * 512);
  }
  // permuted K source row (LDS slot s=16c+4q+r holds key 32(c&1)+8q+4(c>>1)+r)
  const int kperm = 32 * (w & 1) + 4 * (w >> 1) + 8 * (sr >> 2) + (sr & 3);
  const u16* Kg0 = QK + baseq + 1024 + (size_t)kperm * QS + gch * 8;
  const u16* Vg0 = Vt + vbase + (size_t)(w * 16 + sr) * S + gch * 8;
  __syncthreads();  // Q staged (also publishes Tbl)

  // Q fragments -> registers: aq[strip][ks]
  bf16x8 aq[4][2];
#pragma unroll
  for (int s = 0; s < 4; s++)
#pragma unroll
    for (int ks = 0; ks < 2; ks++)
      aq[s][ks] = *(const bf16x8*)&SM[w * 4096 + (s * 16 + lc) * 64 + (((ks * 4 + quad) ^ lx) << 3)];
  __syncthreads();  // all aq reads done before K/V staging overwrites region

  // prefetch tile 0 (K rows permuted: i=0 -> +0, i=1 -> +16 rows)
  async16(Kg0, SM + w * 1024);
  async16(Kg0 + (size_t)16 * QS, SM + w * 1024 + 512);
  async16(Vg0, SM + 8192 + w * 1024);
  async16(Vg0 + (size_t)8 * S, SM + 8192 + w * 1024 + 512);

  // mask word pointer: row = q0+w*64+s*16+lc; word = t0/64
  const u64* mptr = mbits + (size_t)(q0 + w * 64 + lc);
  const int sh8 = quad << 3;

  bf16x8 ones;
#pragma unroll
  for (int j = 0; j < 8; j++) ones[j] = (short)0x3F80;  // bf16 1.0

  const f32x4 z = {};  // hoisted zero quad: C operand for first MFMA of each chain
  f32x4 acco[4][4] = {};
  f32x4 accl[4] = {};

  for (int t0 = 0; t0 < S; t0 += 64) {
    const int cur = (t0 >> 6) & 1;
    const u16* Kc = SM + cur * 4096;
    const u16* Vc = SM + 8192 + cur * 4096;
    __syncthreads();  // buf[cur] staged; all waves done with buf[cur^1]
    if (t0 + 64 < S) {
      u16* Kn = SM + (cur ^ 1) * 4096;
      u16* Vn = SM + 8192 + (cur ^ 1) * 4096;
      const u16* Kg = Kg0 + (size_t)(t0 + 64) * QS;
      const u16* Vg = Vg0 + (t0 + 64);
      async16(Kg, Kn + w * 1024);
      async16(Kg + (size_t)16 * QS, Kn + w * 1024 + 512);
      async16(Vg, Vn + w * 1024);
      async16(Vg + (size_t)8 * S, Vn + w * 1024 + 512);
    }

    // mask words for this tile (issue early; consumed after QK)
    u64 mw0 = mptr[(size_t)(t0 >> 6) * 2048];
    u64 mw1 = mptr[(size_t)(t0 >> 6) * 2048 + 16];
    u64 mw2 = mptr[(size_t)(t0 >> 6) * 2048 + 32];
    u64 mw3 = mptr[(size_t)(t0 >> 6) * 2048 + 48];

    // ---- phase 1: K fragments once, then ALL QK MFMAs (4 strips) ----
    bf16x8 bk0[4], bk1[4];
#pragma unroll
    for (int ct = 0; ct < 4; ct++) {
      bk0[ct] = *(const bf16x8*)&Kc[(ct * 16 + lc) * 64 + ((quad ^ lx) << 3)];
      bk1[ct] = *(const bf16x8*)&Kc[(ct * 16 + lc) * 64 + (((4 + quad) ^ lx) << 3)];
    }
    f32x4 sacc[4][4];
    __builtin_amdgcn_s_setprio(1);
#pragma unroll
    for (int s = 0; s < 4; s++)
#pragma unroll
      for (int ct = 0; ct < 4; ct++)
        sacc[s][ct] = __builtin_amdgcn_mfma_f32_16x16x32_bf16(bk0[ct], aq[s][0], z, 0, 0, 0);
#pragma unroll
    for (int s = 0; s < 4; s++)
#pragma unroll
      for (int ct = 0; ct < 4; ct++)
        sacc[s][ct] = __builtin_amdgcn_mfma_f32_16x16x32_bf16(bk1[ct], aq[s][1], sacc[s][ct], 0, 0, 0);
    __builtin_amdgcn_s_setprio(0);

    // ---- phase 2: V fragments once; per-strip softmax+PV ----
    bf16x8 bv0[4], bv1[4];
#pragma unroll
    for (int ct = 0; ct < 4; ct++) {
      bv0[ct] = *(const bf16x8*)&Vc[(ct * 16 + lc) * 64 + ((quad ^ lx) << 3)];
      bv1[ct] = *(const bf16x8*)&Vc[(ct * 16 + lc) * 64 + (((4 + quad) ^ lx) << 3)];
    }

#pragma unroll
    for (int s = 0; s < 4; s++) {
      const u64 mw = (s == 0) ? mw0 : (s == 1) ? mw1 : (s == 2) ? mw2 : mw3;
      uint4 ma = Tbl[((unsigned)mw >> sh8) & 255u];
      uint4 mb = Tbl[((unsigned)(mw >> 32) >> sh8) & 255u];
      unsigned pu[4][4];
#pragma unroll
      for (int ct = 0; ct < 4; ct++)
#pragma unroll
        for (int r = 0; r < 4; r++)
          pu[ct][r] = __float_as_uint(fast_exp2(sacc[s][ct][r]));
      // frag[ks] keys 32ks+8quad+{0..7}; AND-words in key-sequential pair order
      union { unsigned u[4]; bf16x8 v; } f0, f1;
      f0.u[0] = pk_bf16(pu[0][1], pu[0][0]) & ma.x;
      f0.u[1] = pk_bf16(pu[0][3], pu[0][2]) & ma.y;
      f0.u[2] = pk_bf16(pu[2][1], pu[2][0]) & ma.z;
      f0.u[3] = pk_bf16(pu[2][3], pu[2][2]) & ma.w;
      f1.u[0] = pk_bf16(pu[1][1], pu[1][0]) & mb.x;
      f1.u[1] = pk_bf16(pu[1][3], pu[1][2]) & mb.y;
      f1.u[2] = pk_bf16(pu[3][1], pu[3][0]) & mb.z;
      f1.u[3] = pk_bf16(pu[3][3], pu[3][2]) & mb.w;

      __builtin_amdgcn_s_setprio(1);
#pragma unroll
      for (int ct = 0; ct < 4; ct++)
        acco[s][ct] = __builtin_amdgcn_mfma_f32_16x16x32_bf16(f0.v, bv0[ct], acco[s][ct], 0, 0, 0);
      accl[s] = __builtin_amdgcn_mfma_f32_16x16x32_bf16(f0.v, ones, accl[s], 0, 0, 0);
#pragma unroll
      for (int ct = 0; ct < 4; ct++)
        acco[s][ct] = __builtin_amdgcn_mfma_f32_16x16x32_bf16(f1.v, bv1[ct], acco[s][ct], 0, 0, 0);
      accl[s] = __builtin_amdgcn_mfma_f32_16x16x32_bf16(f1.v, ones, accl[s], 0, 0, 0);
      __builtin_amdgcn_s_setprio(0);
    }
  }

#pragma unroll
  for (int s = 0; s < 4; s++)
#pragma unroll
    for (int r = 0; r < 4; r++) {
      float inv = 1.0f / accl[s][r];
      size_t row = (size_t)b * S + q0 + w * 64 + s * 16 + quad * 4 + r;
#pragma unroll
      for (int ct = 0; ct < 4; ct++)
        AO[row * D + h * 64 + ct * 16 + lc] = f2bf(acco[s][ct][r] * inv);
    }
}

// ---------------- output projection GEMM (f32 out) ----------------
// R8: same single-barrier double-buffer transform as qkv_gemm.

__global__ __launch_bounds__(256) void out_gemm(const u16* __restrict__ A, const u16* __restrict__ Bt,
                                                const float* __restrict__ bias, float* __restrict__ C) {
  __shared__ __align__(16) u16 As[2][128 * 32];
  __shared__ __align__(16) u16 Bs[2][128 * 32];
  const int tid = threadIdx.x;
  const int w = tid >> 6, lane = tid & 63, quad = lane >> 4, lc = lane & 15;
  const int K = 1024, N = 1024;
  const int m0 = blockIdx.x * 128, n0 = blockIdx.y * 128;
  const int wrow = (w >> 1) * 64, wcol = (w & 1) * 64;
  const int srow = tid >> 2, sc = tid & 3;
  const u16* Ag = A + (size_t)(m0 + srow) * K + sc * 8;
  const u16* Bg = Bt + (size_t)(n0 + srow) * K + sc * 8;

  // prologue: stage k0=0 into buf 0
  async16(Ag, As[0] + w * 512);
  async16(Ag + (size_t)64 * K, As[0] + w * 512 + 2048);
  async16(Bg, Bs[0] + w * 512);
  async16(Bg + (size_t)64 * K, Bs[0] + w * 512 + 2048);

  f32x4 acc[4][4] = {};
  for (int k0 = 0; k0 < K; k0 += 32) {
    const int cur = (k0 >> 5) & 1;
    __syncthreads();  // buf[cur] staged
    if (k0 + 32 < K) {
      async16(Ag + k0 + 32, As[cur ^ 1] + w * 512);
      async16(Ag + k0 + 32 + (size_t)64 * K, As[cur ^ 1] + w * 512 + 2048);
      async16(Bg + k0 + 32, Bs[cur ^ 1] + w * 512);
      async16(Bg + k0 + 32 + (size_t)64 * K, Bs[cur ^ 1] + w * 512 + 2048);
    }
    bf16x8 af[4], bfr[4];
#pragma unroll
    for (int rt = 0; rt < 4; rt++) af[rt] = *(const bf16x8*)&As[cur][(wrow + rt * 16 + lc) * 32 + quad * 8];
#pragma unroll
    for (int ct = 0; ct < 4; ct++) bfr[ct] = *(const bf16x8*)&Bs[cur][(wcol + ct * 16 + lc) * 32 + quad * 8];
#pragma unroll
    for (int rt = 0; rt < 4; rt++)
#pragma unroll
      for (int ct = 0; ct < 4; ct++)
        acc[rt][ct] = __builtin_amdgcn_mfma_f32_16x16x32_bf16(af[rt], bfr[ct], acc[rt][ct], 0, 0, 0);
  }
#pragma unroll
  for (int ct = 0; ct < 4; ct++) {
    int col = n0 + wcol + ct * 16 + lc;
    float bv = bias[col];
#pragma unroll
    for (int rt = 0; rt < 4; rt++)
#pragma unroll
      for (int r = 0; r < 4; r++) {
        int row = m0 + wrow + rt * 16 + quad * 4 + r;
        C[(size_t)row * N + col] = acc[rt][ct][r] + bv;
      }
  }
}

// ---------------- launcher ----------------

extern "C" void kernel_launch(void* const* d_in, const int* in_sizes, int n_in,
                              void* d_out, int out_size, void* d_ws, size_t ws_size,
                              hipStream_t stream) {
  const int B = 4, S = 2048, D = 1024;
  const float* ctx = (const float*)d_in[0];
  const float* val = (const float*)d_in[1];
  const int*   msk = (const int*)d_in[2];
  const float* Wq  = (const float*)d_in[3];
  const float* bq  = (const float*)d_in[4];
  const float* Wk  = (const float*)d_in[5];
  const float* bk  = (const float*)d_in[6];
  const float* Wv  = (const float*)d_in[7];
  const float* bv  = (const float*)d_in[8];
  const float* Wo  = (const float*)d_in[9];
  const float* bo  = (const float*)d_in[10];
  float* out = (float*)d_out;

  char* ws = (char*)d_ws;
  size_t off = 0;
  auto alloc = [&](size_t sz) { void* p = ws + off; off += (sz + 255) & ~255ULL; return p; };
  const size_t NTOK = (size_t)B * S * D;  // 8388608
  u16* Xc  = (u16*)alloc(NTOK * 2);
  u16* Xv  = (u16*)alloc(NTOK * 2);
  u16* Wqt = (u16*)alloc((size_t)D * D * 2);   // Wqt/Wkt contiguous: fused B matrix
  u16* Wkt = (u16*)alloc((size_t)D * D * 2);
  u16* Wvt = (u16*)alloc((size_t)D * D * 2);
  u16* WoB = (u16*)alloc((size_t)D * D * 2);
  u16* QKb = (u16*)alloc(NTOK * 4);            // fused QK output [B*S][2048]
  u16* Vtg = (u16*)alloc(NTOK * 2);            // V transposed: [bh][dk][S]
  u64* mbits = (u64*)alloc((size_t)S * S / 8); // transposed: [word 0..31][row 0..2047]
  float* bqk = (float*)alloc(2048 * 4);
  u16* AO = Xc;  // alias: Xc dead after QKV GEMM (before attention runs)
  if (off > ws_size) return;  // workspace too small -> visible failure, no OOB

  const float qscale = 0.125f * 1.44269504088896f;  // 1/sqrt(DK) * log2(e)

  prep_kernel<<<34568, 256, 0, stream>>>(ctx, val, msk, Wq, Wk, Wv, Wo, bq, bk,
                                         Xc, Xv, Wqt, Wkt, Wvt, WoB, mbits, bqk);

  // fused Q|K|V projections (QK half N=2048 over Xc; V half N=1024 over Xv, transposed out)
  qkv_gemm<<<dim3(B * S / 128, 24), 256, 0, stream>>>(Xc, Xv, Wqt, Wvt, bqk, bv, QKb, Vtg, qscale);

  // attention (v11: merged QK phase, 64 q-rows/wave, 2 blocks/CU)
  attn_kernel<<<dim3(S / 256, B * 16), 256, 0, stream>>>(QKb, Vtg, mbits, AO);

  // output projection (f32 out)
  out_gemm<<<dim3(B * S / 128, D / 128), 256, 0, stream>>>(AO, WoB, bo, out);
}